// Round 14
// baseline (1490.894 us; speedup 1.0000x reference)
//
#include <hip/hip_runtime.h>
#include <hip/hip_bf16.h>

typedef __hip_bfloat16 bf16;

// Problem constants
#define BB   128
#define TT   256
#define CC   384
#define HH   4
#define DH   64
#define LL   6
#define VV   65
#define FFD  1536
#define BT   (BB * TT)   // 32768
#define PLD  136         // P-staging row stride (bf16): 272B = 17x16B, bank-spread

__device__ __forceinline__ float b2f(bf16 h) { return __bfloat162float(h); }
__device__ __forceinline__ bf16  f2b(float f) { return __float2bfloat16(f); }

typedef __bf16 bf16x8 __attribute__((ext_vector_type(8)));
typedef float  f32x4  __attribute__((ext_vector_type(4)));

__device__ __forceinline__ __bf16 f2n(float f) {
  bf16 h = f2b(f);
  return __builtin_bit_cast(__bf16, h);
}

// global(16B) -> LDS direct copy; LDS dest = wave-uniform base + lane*16
__device__ __forceinline__ void gld_lds16(const void* g, void* l) {
  __builtin_amdgcn_global_load_lds(
      (const __attribute__((address_space(1))) unsigned int*)(unsigned long long)g,
      (__attribute__((address_space(3))) unsigned int*)(unsigned long long)l,
      16, 0, 0);
}

// ---------------------------------------------------------------------------
// Detect input dtype: fp32 (flag=1) vs bf16 (flag=0), via tok_emb bit patterns.
// ---------------------------------------------------------------------------
__global__ __launch_bounds__(256) void detect_kernel(const unsigned short* __restrict__ tok,
                                                     int* __restrict__ flag)
{
  __shared__ int cnt;
  if (threadIdx.x == 0) cnt = 0;
  __syncthreads();
  int c = 0;
  for (int i = threadIdx.x; i < 512; i += 256) {
    int e = (tok[i] >> 7) & 0xFF;
    if (e >= 130) c++;
  }
  atomicAdd(&cnt, c);
  __syncthreads();
  if (threadIdx.x == 0) flag[0] = (cnt > 16) ? 1 : 0;
}

__device__ __forceinline__ float load_flag(const void* src, size_t i, int fl) {
  return fl ? ((const float*)src)[i] : b2f(((const bf16*)src)[i]);
}

// Batched canonicalization of all small tensors in ONE launch.
#define NSEG 13
struct ConvBatch {
  const void* src[NSEG];
  bf16*       dst[NSEG];
  int         len[NSEG];
};

__global__ __launch_bounds__(256) void convert_batch_kernel(ConvBatch cb,
                                                            const int* __restrict__ flag)
{
  int seg = blockIdx.y;
  int i = blockIdx.x * 256 + threadIdx.x;
  if (i >= cb.len[seg]) return;
  cb.dst[seg][i] = f2b(load_flag(cb.src[seg], i, flag[0]));
}

// Generic per-layer transpose: in [L][R][Cc] -> out [L][Cc][R] (bf16), coalesced out.
__global__ __launch_bounds__(256) void transpose_w(const void* __restrict__ src,
                                                   bf16* __restrict__ dst,
                                                   int R, int Cc, int total,
                                                   const int* __restrict__ flag)
{
  int o = blockIdx.x * 256 + threadIdx.x;
  if (o >= total) return;
  int i2 = o % R;
  int j  = (o / R) % Cc;
  int l  = o / (R * Cc);
  dst[o] = f2b(load_flag(src, ((size_t)(l * R + i2)) * Cc + j, flag[0]));
}

// Wlm^T padded repack: dst[n][c] (n<128) = Wlm[c][n] for n<65 else 0.
__global__ __launch_bounds__(256) void repack_lmT(const void* __restrict__ wlm,
                                                  bf16* __restrict__ dst,
                                                  const int* __restrict__ flag)
{
  int o = blockIdx.x * 256 + threadIdx.x;   // total = 128*CC
  if (o >= 128 * CC) return;
  int c = o % CC;
  int n = o / CC;
  float v = (n < VV) ? load_flag(wlm, (size_t)c * VV + n, flag[0]) : 0.f;
  dst[o] = f2b(v);
}

// Fused QKV B^T repack: dst[l][n][c] (n in 0..767) from Wq/Wk/Wv [L,H,C,HS].
__global__ __launch_bounds__(256) void repack_qkvT(const void* __restrict__ wq,
                                                   const void* __restrict__ wk,
                                                   const void* __restrict__ wv,
                                                   bf16* __restrict__ dst,
                                                   const int* __restrict__ flag)
{
  int o = blockIdx.x * 256 + threadIdx.x;   // total = LL*768*CC
  if (o >= LL * 768 * CC) return;
  int c = o % CC;
  int n = (o / CC) % 768;
  int l = o / (CC * 768);
  const void* src = (n < 256) ? wq : (n < 512) ? wk : wv;
  int h = (n >> 6) & 3, d = n & 63;
  dst[o] = f2b(load_flag(src, (((size_t)(l * HH + h)) * CC + c) * DH + d, flag[0]));
}

// ---------------------------------------------------------------------------
// Embedding: x[bt, c] = tok_emb[idx[bt], c] + pos_emb[bt % T, c]   (bf16 out)
// ---------------------------------------------------------------------------
__global__ __launch_bounds__(CC) void embed_kernel(
    const int* __restrict__ idx, const bf16* __restrict__ tok,
    const bf16* __restrict__ pos, bf16* __restrict__ x)
{
  int bt = blockIdx.x;
  int c  = threadIdx.x;
  int tok_id = idx[bt];
  int t = bt & (TT - 1);
  x[(size_t)bt * CC + c] = f2b(b2f(tok[(size_t)tok_id * CC + c]) + b2f(pos[(size_t)t * CC + c]));
}

// ---------------------------------------------------------------------------
// LayerNorm: bf16 x row -> bf16 xn row. One wave per row (C=384 -> 6/lane).
// ---------------------------------------------------------------------------
__global__ __launch_bounds__(256) void ln_kernel(
    const bf16* __restrict__ x, bf16* __restrict__ xn,
    const bf16* __restrict__ g, const bf16* __restrict__ b)
{
  int lane = threadIdx.x & 63;
  int wid  = threadIdx.x >> 6;
  int r = blockIdx.x * 4 + wid;
  const bf16* xr = x + (size_t)r * CC;
  float vals[6];
  float s = 0.f, ss = 0.f;
#pragma unroll
  for (int i = 0; i < 6; ++i) {
    float v = b2f(xr[lane + i * 64]);
    vals[i] = v; s += v; ss += v * v;
  }
#pragma unroll
  for (int off = 32; off; off >>= 1) {
    s  += __shfl_xor(s, off, 64);
    ss += __shfl_xor(ss, off, 64);
  }
  float mu   = s * (1.f / CC);
  float var  = ss * (1.f / CC) - mu * mu;
  float rstd = rsqrtf(var + 1e-5f);
  bf16* xo = xn + (size_t)r * CC;
#pragma unroll
  for (int i = 0; i < 6; ++i) {
    int c = lane + i * 64;
    xo[c] = f2b((vals[i] - mu) * rstd * b2f(g[c]) + b2f(b[c]));
  }
}

// ---------------------------------------------------------------------------
// MFMA GEMM v5: C[M,N] = A[M,K](bf16) * B^T[N,K](bf16) (+bias), epilogues.
// BM=128, BN template (128 or 64), BK=64, 4 waves, counted-vmcnt pipeline,
// bijective XCD swizzle.
//   BN=128: 2-deep (2 buffers, 64KB LDS, 2 blocks/CU), waves 2x2 of 64x64
//   BN= 64: 3-deep (3 buffers, 72KB LDS, 2 blocks/CU), waves 4x1 of 32x64
//           -> loads get 2 K-steps (~800cy) to cover ~900cy HBM latency
// OUT_RES: bf16 residual RMW (fp32 add, bf16 store; each (m,n) single-owner).
// ---------------------------------------------------------------------------
enum { OUT_BF16 = 0, OUT_QKV = 1, OUT_RES = 2, OUT_LMH = 3 };

template<int MODE, bool RELU, int BN>
__global__ __launch_bounds__(256) void mfma_gemm(
    const bf16* __restrict__ A, const bf16* __restrict__ Bt,
    const bf16* __restrict__ bias, void* __restrict__ out,
    int M, int N, int K)
{
  constexpr int MI = (BN == 128) ? 4 : 2;
  constexpr int NI = 4;
  constexpr int BSTG = (BN == 128) ? 4 : 2;   // B stage insts/wave
  constexpr int NBUF = (BN == 128) ? 2 : 3;   // pipeline depth
  __shared__ bf16 As[NBUF][128 * 64];
  __shared__ bf16 Bs[NBUF][BN * 64];
  const int tid  = threadIdx.x;
  const int w    = tid >> 6, lane = tid & 63;

  // bijective XCD swizzle over (x,y) grid; launch guarantees nwg % 8 == 0
  const int nbx  = gridDim.x;
  const int nwg  = nbx * gridDim.y;
  const int orig = blockIdx.y * nbx + blockIdx.x;
  const int swz  = (orig & 7) * (nwg >> 3) + (orig >> 3);
  const int m0   = (swz / nbx) * 128, n0 = (swz % nbx) * BN;

  const int wr   = (BN == 128) ? (w >> 1) * 64 : w * 32;
  const int wc   = (BN == 128) ? (w & 1) * 64 : 0;
  const int lrow = lane & 15, lk = lane >> 4;
  const int srow8 = lane >> 3, sup = lane & 7;

  const int nsteps = K / 64;
  f32x4 acc[MI][NI] = {};

  auto stage = [&](int buf, int k0) {
#pragma unroll
    for (int i = 0; i < 4; ++i) {
      int row  = w * 32 + i * 8 + srow8;
      int ulog = sup ^ (row & 7);       // pre-swizzled global source unit
      gld_lds16(A + (size_t)(m0 + row) * K + k0 + ulog * 8, &As[buf][(w * 32 + i * 8) * 64]);
    }
#pragma unroll
    for (int i = 0; i < BSTG; ++i) {
      int row  = w * (BSTG * 8) + i * 8 + srow8;
      int ulog = sup ^ (row & 7);
      gld_lds16(Bt + (size_t)(n0 + row) * K + k0 + ulog * 8, &Bs[buf][(w * (BSTG * 8) + i * 8) * 64]);
    }
  };

  stage(0, 0);
  if (NBUF == 3 && nsteps > 1) stage(1, 64);

  for (int t = 0; t < nsteps; ++t) {
    const int cur = (NBUF == 2) ? (t & 1) : (t % 3);
    if (NBUF == 2) {
      if (t + 1 < nsteps) {
        stage(cur ^ 1, (t + 1) * 64);
        asm volatile("s_waitcnt vmcnt(8)" ::: "memory");   // oldest 8 (buf cur) done
      } else {
        asm volatile("s_waitcnt vmcnt(0)" ::: "memory");
      }
    } else {
      if (t + 2 < nsteps) {
        stage((t + 2) % 3, (t + 2) * 64);
        asm volatile("s_waitcnt vmcnt(12)" ::: "memory");  // 2 stages (12) in flight
      } else if (t + 1 < nsteps) {
        asm volatile("s_waitcnt vmcnt(6)" ::: "memory");   // 1 stage in flight
      } else {
        asm volatile("s_waitcnt vmcnt(0)" ::: "memory");
      }
    }
    __builtin_amdgcn_s_barrier();                          // all waves: buf[cur] ready
    __builtin_amdgcn_sched_barrier(0);

    bf16x8 af[2][MI], bg[2][NI];
#pragma unroll
    for (int kk = 0; kk < 2; ++kk) {
#pragma unroll
      for (int mi = 0; mi < MI; ++mi) {
        int r = wr + mi * 16 + lrow;
        int u = (kk * 4 + lk) ^ (r & 7);                   // swizzled read
        af[kk][mi] = *reinterpret_cast<const bf16x8*>(&As[cur][r * 64 + u * 8]);
      }
#pragma unroll
      for (int ni = 0; ni < NI; ++ni) {
        int rb = wc + ni * 16 + lrow;
        int ub = (kk * 4 + lk) ^ (rb & 7);
        bg[kk][ni] = *reinterpret_cast<const bf16x8*>(&Bs[cur][rb * 64 + ub * 8]);
      }
    }
    asm volatile("s_waitcnt lgkmcnt(0)" ::: "memory");     // frags in regs
    __builtin_amdgcn_sched_barrier(0);
    __builtin_amdgcn_s_barrier();                          // buf[cur] free for reuse
    // MFMA cluster (register-only) overlaps the in-flight stages
#pragma unroll
    for (int kk = 0; kk < 2; ++kk)
#pragma unroll
      for (int mi = 0; mi < MI; ++mi)
#pragma unroll
        for (int ni = 0; ni < NI; ++ni)
          acc[mi][ni] = __builtin_amdgcn_mfma_f32_16x16x32_bf16(af[kk][mi], bg[kk][ni], acc[mi][ni], 0, 0, 0);
  }

  // Epilogue. D layout: col = lane&15, row = (lane>>4)*4 + r
#pragma unroll
  for (int mi = 0; mi < MI; ++mi) {
#pragma unroll
    for (int ni = 0; ni < NI; ++ni) {
#pragma unroll
      for (int r = 0; r < 4; ++r) {
        int m = m0 + wr + mi * 16 + lk * 4 + r;
        int n = n0 + wc + ni * 16 + lrow;
        float v = acc[mi][ni][r];
        if (MODE == OUT_BF16) {
          v += b2f(bias[n]);
          if (RELU) v = fmaxf(v, 0.f);
          reinterpret_cast<bf16*>(out)[(size_t)m * N + n] = f2b(v);
        } else if (MODE == OUT_RES) {
          v += b2f(bias[n]);
          bf16* xp = reinterpret_cast<bf16*>(out) + (size_t)m * N + n;
          *xp = f2b(b2f(*xp) + v);                         // bf16 residual RMW
        } else if (MODE == OUT_LMH) {
          if (n < VV)
            reinterpret_cast<float*>(out)[(size_t)m * VV + n] = v + b2f(bias[n]);
        } else {  // OUT_QKV: n<256 q, <512 k, else v; scatter to [B,H,T,DH]
          int which = n >> 8;
          int h = (n >> 6) & 3, d = n & 63;
          int b = m >> 8, trow = m & 255;
          reinterpret_cast<bf16*>(out)[(size_t)which * BB * HH * TT * DH +
              (((size_t)b * HH + h) * TT + trow) * DH + d] = f2b(v);
        }
      }
    }
  }
}

// ---------------------------------------------------------------------------
// MFMA flash attention. One block per (b,h), 512 threads (8 waves).
// ---------------------------------------------------------------------------
__global__ __launch_bounds__(512) void attn_mfma_kernel(
    const bf16* __restrict__ qg, const bf16* __restrict__ kg,
    const bf16* __restrict__ vg, bf16* __restrict__ att)
{
  __shared__ __bf16 stage[128 * 64];        // 16KB: K chunk or Vt chunk
  __shared__ __bf16 Pbuf[8][16 * PLD];      // 34KB: per-wave P staging (padded)
  const int bh = blockIdx.x;
  const int b  = bh >> 2, h = bh & 3;       // H = 4
  const int tid = threadIdx.x, w = tid >> 6, lane = tid & 63;
  const int l15 = lane & 15, lk = lane >> 4;
  const bf16* Qg = qg + (size_t)bh * TT * DH;
  const bf16* Kg = kg + (size_t)bh * TT * DH;
  const bf16* Vg = vg + (size_t)bh * TT * DH;
  __bf16* Pw = &Pbuf[w][0];

  for (int qp = 0; qp < 2; ++qp) {
    const int qt = qp ? (15 - w) : w;
    const int mrow0 = qt * 16 + lk * 4;

    bf16x8 aq[2];
#pragma unroll
    for (int kk = 0; kk < 2; ++kk)
      aq[kk] = *reinterpret_cast<const bf16x8*>(Qg + (size_t)(qt * 16 + l15) * DH + (kk * 4 + lk) * 8);

    f32x4 sc[16];
#pragma unroll
    for (int ct = 0; ct < 16; ++ct) sc[ct] = (f32x4){0.f, 0.f, 0.f, 0.f};

    // ---- S = Q K^T over two K chunks of 128 rows ----
#pragma unroll
    for (int c = 0; c < 2; ++c) {
      {
        int rl = w * 16;
#pragma unroll
        for (int i = 0; i < 2; ++i) {
          int row  = rl + i * 8 + (lane >> 3);
          int ulog = (lane & 7) ^ (row & 7);
          gld_lds16(Kg + (size_t)(c * 128 + row) * DH + ulog * 8, &stage[(rl + i * 8) * DH]);
        }
      }
      __syncthreads();
#pragma unroll
      for (int ctl = 0; ctl < 8; ++ctl) {
        int srow = ctl * 16 + l15;
        int ct = c * 8 + ctl;
#pragma unroll
        for (int kk = 0; kk < 2; ++kk) {
          bf16x8 kf = *reinterpret_cast<const bf16x8*>(
              &stage[srow * DH + (((kk * 4 + lk) ^ (srow & 7)) * 8)]);
          sc[ct] = __builtin_amdgcn_mfma_f32_16x16x32_bf16(aq[kk], kf, sc[ct], 0, 0, 0);
        }
      }
      __syncthreads();
    }

    // ---- softmax (registers only) ----
    float mr[4] = {-1e30f, -1e30f, -1e30f, -1e30f};
#pragma unroll
    for (int ct = 0; ct < 16; ++ct) {
      int s = ct * 16 + l15;
#pragma unroll
      for (int r = 0; r < 4; ++r) {
        float v = sc[ct][r] * 0.125f;
        if (s > mrow0 + r) v = -1e30f;
        sc[ct][r] = v;
        mr[r] = fmaxf(mr[r], v);
      }
    }
#pragma unroll
    for (int off = 8; off; off >>= 1)
#pragma unroll
      for (int r = 0; r < 4; ++r) mr[r] = fmaxf(mr[r], __shfl_xor(mr[r], off, 64));
    float dsum[4] = {0.f, 0.f, 0.f, 0.f};
#pragma unroll
    for (int ct = 0; ct < 16; ++ct)
#pragma unroll
      for (int r = 0; r < 4; ++r) {
        float e = __expf(sc[ct][r] - mr[r]);
        sc[ct][r] = e;
        dsum[r] += e;
      }
#pragma unroll
    for (int off = 8; off; off >>= 1)
#pragma unroll
      for (int r = 0; r < 4; ++r) dsum[r] += __shfl_xor(dsum[r], off, 64);
    float rd[4];
#pragma unroll
    for (int r = 0; r < 4; ++r) rd[r] = 1.f / dsum[r];

    // ---- O = P V over two V chunks of 128 keys ----
    f32x4 o[4];
#pragma unroll
    for (int nt = 0; nt < 4; ++nt) o[nt] = (f32x4){0.f, 0.f, 0.f, 0.f};

#pragma unroll
    for (int c = 0; c < 2; ++c) {
      {
        int d0 = w * 8;
#pragma unroll
        for (int it = 0; it < 2; ++it) {
          int sl = it * 64 + lane;
          bf16x8 vv = *reinterpret_cast<const bf16x8*>(Vg + (size_t)(c * 128 + sl) * DH + d0);
#pragma unroll
          for (int j = 0; j < 8; ++j) {
            int u = (sl >> 3) ^ j;
            stage[(d0 + j) * 128 + u * 8 + (sl & 7)] = vv[j];
          }
        }
      }
      __syncthreads();
#pragma unroll
      for (int ctl = 0; ctl < 8; ++ctl) {
        int sl = ctl * 16 + l15;
        int u  = sl >> 3;
#pragma unroll
        for (int r = 0; r < 4; ++r) {
          int row = lk * 4 + r;
          Pw[row * PLD + ((u ^ (row & 7)) * 8) + (sl & 7)] = f2n(sc[c * 8 + ctl][r]);
        }
      }
#pragma unroll
      for (int ks = 0; ks < 4; ++ks) {
        bf16x8 pf = *reinterpret_cast<const bf16x8*>(
            &Pw[l15 * PLD + (((ks * 4 + lk) ^ (l15 & 7)) * 8)]);
#pragma unroll
        for (int nt = 0; nt < 4; ++nt) {
          int dd = nt * 16 + l15;
          bf16x8 vf = *reinterpret_cast<const bf16x8*>(
              &stage[dd * 128 + (((ks * 4 + lk) ^ (dd & 7)) * 8)]);
          o[nt] = __builtin_amdgcn_mfma_f32_16x16x32_bf16(pf, vf, o[nt], 0, 0, 0);
        }
      }
      __syncthreads();
    }

#pragma unroll
    for (int nt = 0; nt < 4; ++nt)
#pragma unroll
      for (int r = 0; r < 4; ++r) {
        int t = qt * 16 + lk * 4 + r;
        int d = nt * 16 + l15;
        att[(((size_t)b * TT + t) * HH + h) * DH + d] = f2b(o[nt][r] * rd[r]);
      }
    __syncthreads();
  }
}

// ---------------------------------------------------------------------------
// Loss + d_out write from fp32 logits scratch. 1024 blocks x 4 waves; each
// wave handles 8 rows; ONE atomic per block.
// ---------------------------------------------------------------------------
__global__ __launch_bounds__(256) void loss_kernel(
    const float* __restrict__ logits, const int* __restrict__ targets,
    void* __restrict__ out, float* __restrict__ loss,
    const int* __restrict__ flag)
{
  __shared__ float wsums[4];
  int wid = threadIdx.x >> 6, lane = threadIdx.x & 63;
  int fl = flag[0];
  float wacc = 0.f;

  for (int i = 0; i < 8; ++i) {
    int r = (blockIdx.x * 4 + wid) * 8 + i;
    const float* lr = logits + (size_t)r * VV;
    float a0 = lr[lane];
    float a1 = (lane == 0) ? lr[64] : -1e30f;

    if (fl) {
      float* o = (float*)out;
      o[(size_t)r * VV + lane] = a0;
      if (lane == 0) o[(size_t)r * VV + 64] = a1;
    } else {
      bf16* o = (bf16*)out;
      o[(size_t)r * VV + lane] = f2b(a0);
      if (lane == 0) o[(size_t)r * VV + 64] = f2b(a1);
    }

    float m = fmaxf(a0, a1);
#pragma unroll
    for (int off = 32; off; off >>= 1) m = fmaxf(m, __shfl_xor(m, off, 64));
    float e = __expf(a0 - m) + ((lane == 0) ? __expf(a1 - m) : 0.f);
#pragma unroll
    for (int off = 32; off; off >>= 1) e += __shfl_xor(e, off, 64);
    float logZ = m + logf(e);
    int tgt = targets[r];
    float contrib = (lane == tgt) ? (a0 - logZ) : 0.f;
    if (lane == 0 && tgt == 64) contrib = a1 - logZ;
#pragma unroll
    for (int off = 32; off; off >>= 1) contrib += __shfl_xor(contrib, off, 64);
    wacc += contrib;
  }

  if (lane == 0) wsums[wid] = wacc;
  __syncthreads();
  if (threadIdx.x == 0)
    atomicAdd(loss, -(wsums[0] + wsums[1] + wsums[2] + wsums[3]));
}

__global__ void finalize_kernel(const float* __restrict__ loss, void* __restrict__ out,
                                const int* __restrict__ flag)
{
  float v = loss[0] * (1.f / BT);
  if (flag[0]) ((float*)out)[(size_t)BT * VV] = v;
  else         ((bf16*)out)[(size_t)BT * VV]  = f2b(v);
}

// ---------------------------------------------------------------------------
extern "C" void kernel_launch(void* const* d_in, const int* in_sizes, int n_in,
                              void* d_out, int out_size, void* d_ws, size_t ws_size,
                              hipStream_t stream)
{
  const int* idx     = (const int*)d_in[0];
  const int* targets = (const int*)d_in[1];
  const void* tok  = d_in[2];
  const void* pos  = d_in[3];
  const void* Wq   = d_in[4];
  const void* Wk   = d_in[5];
  const void* Wv   = d_in[6];
  const void* Wo   = d_in[7];
  const void* bo   = d_in[8];
  const void* W1   = d_in[9];
  const void* b1   = d_in[10];
  const void* W2   = d_in[11];
  const void* b2   = d_in[12];
  const void* ln1g = d_in[13];
  const void* ln1b = d_in[14];
  const void* ln2g = d_in[15];
  const void* ln2b = d_in[16];
  const void* lnfg = d_in[17];
  const void* lnfb = d_in[18];
  const void* Wlm  = d_in[19];
  const void* blm  = d_in[20];

  char* ws = (char*)d_ws;
  size_t off = 0;
  auto alloc = [&](size_t bytes) { void* p = ws + off; off += (bytes + 255) & ~(size_t)255; return p; };

  bf16*  x   = (bf16*)alloc((size_t)BT * CC * 2);             // 25.2 MB (bf16 residual)
  bf16*  xn  = (bf16*)alloc((size_t)BT * CC * 2);             // 25.2 MB
  bf16*  qb  = (bf16*)alloc((size_t)BB * HH * TT * DH * 2);   // 16.8 MB x3 (contiguous)
  bf16*  kb  = (bf16*)alloc((size_t)BB * HH * TT * DH * 2);
  bf16*  vb  = (bf16*)alloc((size_t)BB * HH * TT * DH * 2);
  bf16*  att = (bf16*)alloc((size_t)BT * 256 * 2);            // 16.8 MB
  float* logits = (float*)att;  // logits scratch aliases dead att (8.5MB <= 16.8MB)
  // canonical bf16 weights
  bf16* c_tok  = (bf16*)alloc((size_t)VV * CC * 2);
  bf16* c_pos  = (bf16*)alloc((size_t)TT * CC * 2);
  bf16* wqkvT  = (bf16*)alloc((size_t)LL * 768 * CC * 2);     // B^T for fused QKV
  bf16* woT    = (bf16*)alloc((size_t)LL * CC * 256 * 2);     // B^T [C][256]
  bf16* w1T    = (bf16*)alloc((size_t)LL * FFD * CC * 2);     // B^T [FFD][C]
  bf16* w2T    = (bf16*)alloc((size_t)LL * CC * FFD * 2);     // B^T [C][FFD]
  bf16* wlmT   = (bf16*)alloc((size_t)128 * CC * 2);          // B^T [128][C], rows>=65 zero
  bf16* c_bo   = (bf16*)alloc((size_t)LL * CC * 2);
  bf16* c_b1   = (bf16*)alloc((size_t)LL * FFD * 2);
  bf16* c_b2   = (bf16*)alloc((size_t)LL * CC * 2);
  bf16* c_l1g  = (bf16*)alloc((size_t)LL * CC * 2);
  bf16* c_l1b  = (bf16*)alloc((size_t)LL * CC * 2);
  bf16* c_l2g  = (bf16*)alloc((size_t)LL * CC * 2);
  bf16* c_l2b  = (bf16*)alloc((size_t)LL * CC * 2);
  bf16* c_lfg  = (bf16*)alloc((size_t)CC * 2);
  bf16* c_lfb  = (bf16*)alloc((size_t)CC * 2);
  bf16* c_blm  = (bf16*)alloc((size_t)VV * 2);
  float* loss  = (float*)alloc(256);
  int*   flag  = (int*)alloc(256);

  // FF intermediate: full-size if ws permits, else 2-chunk aliased over q/k/v.
  size_t ff1_full_bytes = (size_t)BT * FFD * 2;               // 100.7 MB
  int    nchunks;
  int    fch;
  bf16*  ff1;
  if (ws_size - off >= ff1_full_bytes + 256) {
    ff1 = (bf16*)alloc(ff1_full_bytes);
    nchunks = 1; fch = BT;
  } else {
    ff1 = qb;
    nchunks = 2; fch = BT / 2;
  }

  hipMemsetAsync(loss, 0, 4, stream);

  detect_kernel<<<1, 256, 0, stream>>>((const unsigned short*)tok, flag);

  {
    ConvBatch cb;
    const void* srcs[NSEG] = {tok, pos, bo, b1, b2, ln1g, ln1b, ln2g, ln2b, lnfg, lnfb, blm, Wlm};
    bf16* dsts[NSEG] = {c_tok, c_pos, c_bo, c_b1, c_b2, c_l1g, c_l1b, c_l2g, c_l2b, c_lfg, c_lfb, c_blm, nullptr};
    int lens[NSEG] = {VV * CC, TT * CC, LL * CC, LL * FFD, LL * CC, LL * CC, LL * CC,
                      LL * CC, LL * CC, CC, CC, VV, 0};
    int maxlen = 0;
    for (int i = 0; i < NSEG; ++i) {
      cb.src[i] = srcs[i]; cb.dst[i] = dsts[i]; cb.len[i] = lens[i];
      if (lens[i] > maxlen) maxlen = lens[i];
    }
    convert_batch_kernel<<<dim3((maxlen + 255) / 256, NSEG), 256, 0, stream>>>(cb, flag);
  }

  {
    int tq = LL * 768 * CC;
    repack_qkvT<<<(tq + 255) / 256, 256, 0, stream>>>(Wq, Wk, Wv, wqkvT, flag);
    int t1 = LL * 256 * CC;
    transpose_w<<<(t1 + 255) / 256, 256, 0, stream>>>(Wo, woT, 256, CC, t1, flag);
    int t2 = LL * CC * FFD;
    transpose_w<<<(t2 + 255) / 256, 256, 0, stream>>>(W1, w1T, CC, FFD, t2, flag);
    transpose_w<<<(t2 + 255) / 256, 256, 0, stream>>>(W2, w2T, FFD, CC, t2, flag);
    int t3 = 128 * CC;
    repack_lmT<<<(t3 + 255) / 256, 256, 0, stream>>>(Wlm, wlmT, flag);
  }

  embed_kernel<<<BT, CC, 0, stream>>>(idx, c_tok, c_pos, x);

  for (int l = 0; l < LL; ++l) {
    ln_kernel<<<BT / 4, 256, 0, stream>>>(x, xn, c_l1g + l * CC, c_l1b + l * CC);

    mfma_gemm<OUT_QKV, false, 128><<<dim3(768 / 128, BT / 128), 256, 0, stream>>>(
        xn, wqkvT + (size_t)l * 768 * CC, nullptr, qb, BT, 768, CC);

    attn_mfma_kernel<<<BB * HH, 512, 0, stream>>>(qb, kb, vb, att);

    // Wo: N=384 -> BN=64 tiles (3-deep pipeline), grid (6,256)=1536 blocks
    mfma_gemm<OUT_RES, false, 64><<<dim3(CC / 64, BT / 128), 256, 0, stream>>>(
        att, woT + (size_t)l * CC * 256, c_bo + l * CC, x, BT, CC, 256);

    ln_kernel<<<BT / 4, 256, 0, stream>>>(x, xn, c_l2g + l * CC, c_l2b + l * CC);

    for (int ch = 0; ch < nchunks; ++ch) {
      const bf16* Ach = xn + (size_t)ch * fch * CC;
      mfma_gemm<OUT_BF16, true, 128><<<dim3(FFD / 128, fch / 128), 256, 0, stream>>>(
          Ach, w1T + (size_t)l * FFD * CC, c_b1 + l * FFD, ff1, fch, FFD, CC);
      // FF2: N=384 -> BN=64 tiles (3-deep pipeline), grid (6, fch/128)
      mfma_gemm<OUT_RES, false, 64><<<dim3(CC / 64, fch / 128), 256, 0, stream>>>(
          ff1, w2T + (size_t)l * CC * FFD, c_b2 + l * CC, x + (size_t)ch * fch * CC, fch, CC, FFD);
    }
  }

  ln_kernel<<<BT / 4, 256, 0, stream>>>(x, xn, c_lfg, c_lfb);
  // LM head: [BT,384] x [384,65->128] via MFMA, BN=64 -> grid (2,256)=512
  mfma_gemm<OUT_LMH, false, 64><<<dim3(2, BT / 128), 256, 0, stream>>>(
      xn, wlmT, c_blm, logits, BT, 128, CC);
  loss_kernel<<<1024, 256, 0, stream>>>(logits, targets, d_out, loss, flag);
  finalize_kernel<<<1, 1, 0, stream>>>(loss, d_out, flag);
}

// Round 15
// 1435.321 us; speedup vs baseline: 1.0387x; 1.0387x over previous
//
#include <hip/hip_runtime.h>
#include <hip/hip_bf16.h>

typedef __hip_bfloat16 bf16;

// Problem constants
#define BB   128
#define TT   256
#define CC   384
#define HH   4
#define DH   64
#define LL   6
#define VV   65
#define FFD  1536
#define BT   (BB * TT)   // 32768
#define PLD  136         // P-staging row stride (bf16): 272B = 17x16B, bank-spread

__device__ __forceinline__ float b2f(bf16 h) { return __bfloat162float(h); }
__device__ __forceinline__ bf16  f2b(float f) { return __float2bfloat16(f); }

typedef __bf16 bf16x8 __attribute__((ext_vector_type(8)));
typedef float  f32x4  __attribute__((ext_vector_type(4)));

__device__ __forceinline__ __bf16 f2n(float f) {
  bf16 h = f2b(f);
  return __builtin_bit_cast(__bf16, h);
}

// global(16B) -> LDS direct copy; LDS dest = wave-uniform base + lane*16
__device__ __forceinline__ void gld_lds16(const void* g, void* l) {
  __builtin_amdgcn_global_load_lds(
      (const __attribute__((address_space(1))) unsigned int*)(unsigned long long)g,
      (__attribute__((address_space(3))) unsigned int*)(unsigned long long)l,
      16, 0, 0);
}

// ---------------------------------------------------------------------------
// Detect input dtype: fp32 (flag=1) vs bf16 (flag=0), via tok_emb bit patterns.
// ---------------------------------------------------------------------------
__global__ __launch_bounds__(256) void detect_kernel(const unsigned short* __restrict__ tok,
                                                     int* __restrict__ flag)
{
  __shared__ int cnt;
  if (threadIdx.x == 0) cnt = 0;
  __syncthreads();
  int c = 0;
  for (int i = threadIdx.x; i < 512; i += 256) {
    int e = (tok[i] >> 7) & 0xFF;
    if (e >= 130) c++;
  }
  atomicAdd(&cnt, c);
  __syncthreads();
  if (threadIdx.x == 0) flag[0] = (cnt > 16) ? 1 : 0;
}

__device__ __forceinline__ float load_flag(const void* src, size_t i, int fl) {
  return fl ? ((const float*)src)[i] : b2f(((const bf16*)src)[i]);
}

// Batched canonicalization of all small tensors in ONE launch.
#define NSEG 13
struct ConvBatch {
  const void* src[NSEG];
  bf16*       dst[NSEG];
  int         len[NSEG];
};

__global__ __launch_bounds__(256) void convert_batch_kernel(ConvBatch cb,
                                                            const int* __restrict__ flag)
{
  int seg = blockIdx.y;
  int i = blockIdx.x * 256 + threadIdx.x;
  if (i >= cb.len[seg]) return;
  cb.dst[seg][i] = f2b(load_flag(cb.src[seg], i, flag[0]));
}

// Generic per-layer transpose: in [L][R][Cc] -> out [L][Cc][R] (bf16), coalesced out.
__global__ __launch_bounds__(256) void transpose_w(const void* __restrict__ src,
                                                   bf16* __restrict__ dst,
                                                   int R, int Cc, int total,
                                                   const int* __restrict__ flag)
{
  int o = blockIdx.x * 256 + threadIdx.x;
  if (o >= total) return;
  int i2 = o % R;
  int j  = (o / R) % Cc;
  int l  = o / (R * Cc);
  dst[o] = f2b(load_flag(src, ((size_t)(l * R + i2)) * Cc + j, flag[0]));
}

// Wlm^T padded repack: dst[n][c] (n<128) = Wlm[c][n] for n<65 else 0.
__global__ __launch_bounds__(256) void repack_lmT(const void* __restrict__ wlm,
                                                  bf16* __restrict__ dst,
                                                  const int* __restrict__ flag)
{
  int o = blockIdx.x * 256 + threadIdx.x;   // total = 128*CC
  if (o >= 128 * CC) return;
  int c = o % CC;
  int n = o / CC;
  float v = (n < VV) ? load_flag(wlm, (size_t)c * VV + n, flag[0]) : 0.f;
  dst[o] = f2b(v);
}

// Fused QKV B^T repack: dst[l][n][c] (n in 0..767) from Wq/Wk/Wv [L,H,C,HS].
__global__ __launch_bounds__(256) void repack_qkvT(const void* __restrict__ wq,
                                                   const void* __restrict__ wk,
                                                   const void* __restrict__ wv,
                                                   bf16* __restrict__ dst,
                                                   const int* __restrict__ flag)
{
  int o = blockIdx.x * 256 + threadIdx.x;   // total = LL*768*CC
  if (o >= LL * 768 * CC) return;
  int c = o % CC;
  int n = (o / CC) % 768;
  int l = o / (CC * 768);
  const void* src = (n < 256) ? wq : (n < 512) ? wk : wv;
  int h = (n >> 6) & 3, d = n & 63;
  dst[o] = f2b(load_flag(src, (((size_t)(l * HH + h)) * CC + c) * DH + d, flag[0]));
}

// ---------------------------------------------------------------------------
// Embedding: x[bt, c] = tok_emb[idx[bt], c] + pos_emb[bt % T, c]   (bf16 out)
// ---------------------------------------------------------------------------
__global__ __launch_bounds__(CC) void embed_kernel(
    const int* __restrict__ idx, const bf16* __restrict__ tok,
    const bf16* __restrict__ pos, bf16* __restrict__ x)
{
  int bt = blockIdx.x;
  int c  = threadIdx.x;
  int tok_id = idx[bt];
  int t = bt & (TT - 1);
  x[(size_t)bt * CC + c] = f2b(b2f(tok[(size_t)tok_id * CC + c]) + b2f(pos[(size_t)t * CC + c]));
}

// ---------------------------------------------------------------------------
// LayerNorm: bf16 x row -> bf16 xn row. One wave per row (C=384 -> 6/lane).
// ---------------------------------------------------------------------------
__global__ __launch_bounds__(256) void ln_kernel(
    const bf16* __restrict__ x, bf16* __restrict__ xn,
    const bf16* __restrict__ g, const bf16* __restrict__ b)
{
  int lane = threadIdx.x & 63;
  int wid  = threadIdx.x >> 6;
  int r = blockIdx.x * 4 + wid;
  const bf16* xr = x + (size_t)r * CC;
  float vals[6];
  float s = 0.f, ss = 0.f;
#pragma unroll
  for (int i = 0; i < 6; ++i) {
    float v = b2f(xr[lane + i * 64]);
    vals[i] = v; s += v; ss += v * v;
  }
#pragma unroll
  for (int off = 32; off; off >>= 1) {
    s  += __shfl_xor(s, off, 64);
    ss += __shfl_xor(ss, off, 64);
  }
  float mu   = s * (1.f / CC);
  float var  = ss * (1.f / CC) - mu * mu;
  float rstd = rsqrtf(var + 1e-5f);
  bf16* xo = xn + (size_t)r * CC;
#pragma unroll
  for (int i = 0; i < 6; ++i) {
    int c = lane + i * 64;
    xo[c] = f2b((vals[i] - mu) * rstd * b2f(g[c]) + b2f(b[c]));
  }
}

// ---------------------------------------------------------------------------
// MFMA GEMM v3 (round-10 template): C[M,N] = A[M,K](bf16) * B^T[N,K](bf16).
// BM=128, BN template (128 or 64), BK=64, 4 waves, 2-deep double-buffered LDS
// with counted-vmcnt pipeline, bijective XCD swizzle.
//   BN=128: waves 2x2, each 64x64 (MI=4,NI=4), 64KB LDS -> 2 blocks/CU
//   BN= 64: waves 4x1, each 32x64 (MI=2,NI=4), 48KB LDS -> 3 blocks/CU
// Occupancy beats per-wave read ratio on these skinny shapes (r10 vs r11/12/14),
// so ALL N<=1536 GEMMs use BN=64 except none remaining.
// OUT_RES: bf16 residual RMW (fp32 add, bf16 store; each (m,n) single-owner).
// ---------------------------------------------------------------------------
enum { OUT_BF16 = 0, OUT_QKV = 1, OUT_RES = 2, OUT_LMH = 3 };

template<int MODE, bool RELU, int BN>
__global__ __launch_bounds__(256) void mfma_gemm(
    const bf16* __restrict__ A, const bf16* __restrict__ Bt,
    const bf16* __restrict__ bias, void* __restrict__ out,
    int M, int N, int K)
{
  constexpr int MI = (BN == 128) ? 4 : 2;
  constexpr int NI = 4;
  constexpr int BSTG = (BN == 128) ? 4 : 2;   // B stage insts/wave
  __shared__ bf16 As[2][128 * 64];
  __shared__ bf16 Bs[2][BN * 64];
  const int tid  = threadIdx.x;
  const int w    = tid >> 6, lane = tid & 63;

  // bijective XCD swizzle over (x,y) grid; launch guarantees nwg % 8 == 0
  const int nbx  = gridDim.x;
  const int nwg  = nbx * gridDim.y;
  const int orig = blockIdx.y * nbx + blockIdx.x;
  const int swz  = (orig & 7) * (nwg >> 3) + (orig >> 3);
  const int m0   = (swz / nbx) * 128, n0 = (swz % nbx) * BN;

  const int wr   = (BN == 128) ? (w >> 1) * 64 : w * 32;
  const int wc   = (BN == 128) ? (w & 1) * 64 : 0;
  const int lrow = lane & 15, lk = lane >> 4;
  const int srow8 = lane >> 3, sup = lane & 7;

  const int nsteps = K / 64;
  f32x4 acc[MI][NI] = {};

  auto stage = [&](int buf, int k0) {
#pragma unroll
    for (int i = 0; i < 4; ++i) {
      int row  = w * 32 + i * 8 + srow8;
      int ulog = sup ^ (row & 7);       // pre-swizzled global source unit
      gld_lds16(A + (size_t)(m0 + row) * K + k0 + ulog * 8, &As[buf][(w * 32 + i * 8) * 64]);
    }
#pragma unroll
    for (int i = 0; i < BSTG; ++i) {
      int row  = w * (BSTG * 8) + i * 8 + srow8;
      int ulog = sup ^ (row & 7);
      gld_lds16(Bt + (size_t)(n0 + row) * K + k0 + ulog * 8, &Bs[buf][(w * (BSTG * 8) + i * 8) * 64]);
    }
  };

  stage(0, 0);   // prologue: (4+BSTG) loads in flight per wave

  for (int t = 0; t < nsteps; ++t) {
    const int cur = t & 1;
    if (t + 1 < nsteps) {
      stage(cur ^ 1, (t + 1) * 64);
      // oldest (4+BSTG) loads (buf cur) complete; newest stay in flight
      if constexpr (BN == 128) asm volatile("s_waitcnt vmcnt(8)" ::: "memory");
      else                     asm volatile("s_waitcnt vmcnt(6)" ::: "memory");
    } else {
      asm volatile("s_waitcnt vmcnt(0)" ::: "memory");
    }
    __builtin_amdgcn_s_barrier();                        // all waves: buf[cur] ready
    __builtin_amdgcn_sched_barrier(0);

    bf16x8 af[2][MI], bg[2][NI];
#pragma unroll
    for (int kk = 0; kk < 2; ++kk) {
#pragma unroll
      for (int mi = 0; mi < MI; ++mi) {
        int r = wr + mi * 16 + lrow;
        int u = (kk * 4 + lk) ^ (r & 7);                 // swizzled read
        af[kk][mi] = *reinterpret_cast<const bf16x8*>(&As[cur][r * 64 + u * 8]);
      }
#pragma unroll
      for (int ni = 0; ni < NI; ++ni) {
        int rb = wc + ni * 16 + lrow;
        int ub = (kk * 4 + lk) ^ (rb & 7);
        bg[kk][ni] = *reinterpret_cast<const bf16x8*>(&Bs[cur][rb * 64 + ub * 8]);
      }
    }
    asm volatile("s_waitcnt lgkmcnt(0)" ::: "memory");   // frags in regs
    __builtin_amdgcn_sched_barrier(0);
    __builtin_amdgcn_s_barrier();                        // buf[cur] free for reuse
    // MFMA cluster (register-only) overlaps the in-flight stage of tile t+1
#pragma unroll
    for (int kk = 0; kk < 2; ++kk)
#pragma unroll
      for (int mi = 0; mi < MI; ++mi)
#pragma unroll
        for (int ni = 0; ni < NI; ++ni)
          acc[mi][ni] = __builtin_amdgcn_mfma_f32_16x16x32_bf16(af[kk][mi], bg[kk][ni], acc[mi][ni], 0, 0, 0);
  }

  // Epilogue. D layout: col = lane&15, row = (lane>>4)*4 + r
#pragma unroll
  for (int mi = 0; mi < MI; ++mi) {
#pragma unroll
    for (int ni = 0; ni < NI; ++ni) {
#pragma unroll
      for (int r = 0; r < 4; ++r) {
        int m = m0 + wr + mi * 16 + lk * 4 + r;
        int n = n0 + wc + ni * 16 + lrow;
        float v = acc[mi][ni][r];
        if (MODE == OUT_BF16) {
          v += b2f(bias[n]);
          if (RELU) v = fmaxf(v, 0.f);
          reinterpret_cast<bf16*>(out)[(size_t)m * N + n] = f2b(v);
        } else if (MODE == OUT_RES) {
          v += b2f(bias[n]);
          bf16* xp = reinterpret_cast<bf16*>(out) + (size_t)m * N + n;
          *xp = f2b(b2f(*xp) + v);                       // bf16 residual RMW
        } else if (MODE == OUT_LMH) {
          if (n < VV)
            reinterpret_cast<float*>(out)[(size_t)m * VV + n] = v + b2f(bias[n]);
        } else {  // OUT_QKV: n<256 q, <512 k, else v; scatter to [B,H,T,DH]
          int which = n >> 8;
          int h = (n >> 6) & 3, d = n & 63;
          int b = m >> 8, trow = m & 255;
          reinterpret_cast<bf16*>(out)[(size_t)which * BB * HH * TT * DH +
              (((size_t)b * HH + h) * TT + trow) * DH + d] = f2b(v);
        }
      }
    }
  }
}

// ---------------------------------------------------------------------------
// MFMA flash attention. One block per (b,h), 512 threads (8 waves).
// ---------------------------------------------------------------------------
__global__ __launch_bounds__(512) void attn_mfma_kernel(
    const bf16* __restrict__ qg, const bf16* __restrict__ kg,
    const bf16* __restrict__ vg, bf16* __restrict__ att)
{
  __shared__ __bf16 stage[128 * 64];        // 16KB: K chunk or Vt chunk
  __shared__ __bf16 Pbuf[8][16 * PLD];      // 34KB: per-wave P staging (padded)
  const int bh = blockIdx.x;
  const int b  = bh >> 2, h = bh & 3;       // H = 4
  const int tid = threadIdx.x, w = tid >> 6, lane = tid & 63;
  const int l15 = lane & 15, lk = lane >> 4;
  const bf16* Qg = qg + (size_t)bh * TT * DH;
  const bf16* Kg = kg + (size_t)bh * TT * DH;
  const bf16* Vg = vg + (size_t)bh * TT * DH;
  __bf16* Pw = &Pbuf[w][0];

  for (int qp = 0; qp < 2; ++qp) {
    const int qt = qp ? (15 - w) : w;
    const int mrow0 = qt * 16 + lk * 4;

    bf16x8 aq[2];
#pragma unroll
    for (int kk = 0; kk < 2; ++kk)
      aq[kk] = *reinterpret_cast<const bf16x8*>(Qg + (size_t)(qt * 16 + l15) * DH + (kk * 4 + lk) * 8);

    f32x4 sc[16];
#pragma unroll
    for (int ct = 0; ct < 16; ++ct) sc[ct] = (f32x4){0.f, 0.f, 0.f, 0.f};

    // ---- S = Q K^T over two K chunks of 128 rows ----
#pragma unroll
    for (int c = 0; c < 2; ++c) {
      {
        int rl = w * 16;
#pragma unroll
        for (int i = 0; i < 2; ++i) {
          int row  = rl + i * 8 + (lane >> 3);
          int ulog = (lane & 7) ^ (row & 7);
          gld_lds16(Kg + (size_t)(c * 128 + row) * DH + ulog * 8, &stage[(rl + i * 8) * DH]);
        }
      }
      __syncthreads();
#pragma unroll
      for (int ctl = 0; ctl < 8; ++ctl) {
        int srow = ctl * 16 + l15;
        int ct = c * 8 + ctl;
#pragma unroll
        for (int kk = 0; kk < 2; ++kk) {
          bf16x8 kf = *reinterpret_cast<const bf16x8*>(
              &stage[srow * DH + (((kk * 4 + lk) ^ (srow & 7)) * 8)]);
          sc[ct] = __builtin_amdgcn_mfma_f32_16x16x32_bf16(aq[kk], kf, sc[ct], 0, 0, 0);
        }
      }
      __syncthreads();
    }

    // ---- softmax (registers only) ----
    float mr[4] = {-1e30f, -1e30f, -1e30f, -1e30f};
#pragma unroll
    for (int ct = 0; ct < 16; ++ct) {
      int s = ct * 16 + l15;
#pragma unroll
      for (int r = 0; r < 4; ++r) {
        float v = sc[ct][r] * 0.125f;
        if (s > mrow0 + r) v = -1e30f;
        sc[ct][r] = v;
        mr[r] = fmaxf(mr[r], v);
      }
    }
#pragma unroll
    for (int off = 8; off; off >>= 1)
#pragma unroll
      for (int r = 0; r < 4; ++r) mr[r] = fmaxf(mr[r], __shfl_xor(mr[r], off, 64));
    float dsum[4] = {0.f, 0.f, 0.f, 0.f};
#pragma unroll
    for (int ct = 0; ct < 16; ++ct)
#pragma unroll
      for (int r = 0; r < 4; ++r) {
        float e = __expf(sc[ct][r] - mr[r]);
        sc[ct][r] = e;
        dsum[r] += e;
      }
#pragma unroll
    for (int off = 8; off; off >>= 1)
#pragma unroll
      for (int r = 0; r < 4; ++r) dsum[r] += __shfl_xor(dsum[r], off, 64);
    float rd[4];
#pragma unroll
    for (int r = 0; r < 4; ++r) rd[r] = 1.f / dsum[r];

    // ---- O = P V over two V chunks of 128 keys ----
    f32x4 o[4];
#pragma unroll
    for (int nt = 0; nt < 4; ++nt) o[nt] = (f32x4){0.f, 0.f, 0.f, 0.f};

#pragma unroll
    for (int c = 0; c < 2; ++c) {
      {
        int d0 = w * 8;
#pragma unroll
        for (int it = 0; it < 2; ++it) {
          int sl = it * 64 + lane;
          bf16x8 vv = *reinterpret_cast<const bf16x8*>(Vg + (size_t)(c * 128 + sl) * DH + d0);
#pragma unroll
          for (int j = 0; j < 8; ++j) {
            int u = (sl >> 3) ^ j;
            stage[(d0 + j) * 128 + u * 8 + (sl & 7)] = vv[j];
          }
        }
      }
      __syncthreads();
#pragma unroll
      for (int ctl = 0; ctl < 8; ++ctl) {
        int sl = ctl * 16 + l15;
        int u  = sl >> 3;
#pragma unroll
        for (int r = 0; r < 4; ++r) {
          int row = lk * 4 + r;
          Pw[row * PLD + ((u ^ (row & 7)) * 8) + (sl & 7)] = f2n(sc[c * 8 + ctl][r]);
        }
      }
#pragma unroll
      for (int ks = 0; ks < 4; ++ks) {
        bf16x8 pf = *reinterpret_cast<const bf16x8*>(
            &Pw[l15 * PLD + (((ks * 4 + lk) ^ (l15 & 7)) * 8)]);
#pragma unroll
        for (int nt = 0; nt < 4; ++nt) {
          int dd = nt * 16 + l15;
          bf16x8 vf = *reinterpret_cast<const bf16x8*>(
              &stage[dd * 128 + (((ks * 4 + lk) ^ (dd & 7)) * 8)]);
          o[nt] = __builtin_amdgcn_mfma_f32_16x16x32_bf16(pf, vf, o[nt], 0, 0, 0);
        }
      }
      __syncthreads();
    }

#pragma unroll
    for (int nt = 0; nt < 4; ++nt)
#pragma unroll
      for (int r = 0; r < 4; ++r) {
        int t = qt * 16 + lk * 4 + r;
        int d = nt * 16 + l15;
        att[(((size_t)b * TT + t) * HH + h) * DH + d] = f2b(o[nt][r] * rd[r]);
      }
    __syncthreads();
  }
}

// ---------------------------------------------------------------------------
// Loss + d_out write from fp32 logits scratch. 1024 blocks x 4 waves; each
// wave handles 8 rows; ONE atomic per block.
// ---------------------------------------------------------------------------
__global__ __launch_bounds__(256) void loss_kernel(
    const float* __restrict__ logits, const int* __restrict__ targets,
    void* __restrict__ out, float* __restrict__ loss,
    const int* __restrict__ flag)
{
  __shared__ float wsums[4];
  int wid = threadIdx.x >> 6, lane = threadIdx.x & 63;
  int fl = flag[0];
  float wacc = 0.f;

  for (int i = 0; i < 8; ++i) {
    int r = (blockIdx.x * 4 + wid) * 8 + i;
    const float* lr = logits + (size_t)r * VV;
    float a0 = lr[lane];
    float a1 = (lane == 0) ? lr[64] : -1e30f;

    if (fl) {
      float* o = (float*)out;
      o[(size_t)r * VV + lane] = a0;
      if (lane == 0) o[(size_t)r * VV + 64] = a1;
    } else {
      bf16* o = (bf16*)out;
      o[(size_t)r * VV + lane] = f2b(a0);
      if (lane == 0) o[(size_t)r * VV + 64] = f2b(a1);
    }

    float m = fmaxf(a0, a1);
#pragma unroll
    for (int off = 32; off; off >>= 1) m = fmaxf(m, __shfl_xor(m, off, 64));
    float e = __expf(a0 - m) + ((lane == 0) ? __expf(a1 - m) : 0.f);
#pragma unroll
    for (int off = 32; off; off >>= 1) e += __shfl_xor(e, off, 64);
    float logZ = m + logf(e);
    int tgt = targets[r];
    float contrib = (lane == tgt) ? (a0 - logZ) : 0.f;
    if (lane == 0 && tgt == 64) contrib = a1 - logZ;
#pragma unroll
    for (int off = 32; off; off >>= 1) contrib += __shfl_xor(contrib, off, 64);
    wacc += contrib;
  }

  if (lane == 0) wsums[wid] = wacc;
  __syncthreads();
  if (threadIdx.x == 0)
    atomicAdd(loss, -(wsums[0] + wsums[1] + wsums[2] + wsums[3]));
}

__global__ void finalize_kernel(const float* __restrict__ loss, void* __restrict__ out,
                                const int* __restrict__ flag)
{
  float v = loss[0] * (1.f / BT);
  if (flag[0]) ((float*)out)[(size_t)BT * VV] = v;
  else         ((bf16*)out)[(size_t)BT * VV]  = f2b(v);
}

// ---------------------------------------------------------------------------
extern "C" void kernel_launch(void* const* d_in, const int* in_sizes, int n_in,
                              void* d_out, int out_size, void* d_ws, size_t ws_size,
                              hipStream_t stream)
{
  const int* idx     = (const int*)d_in[0];
  const int* targets = (const int*)d_in[1];
  const void* tok  = d_in[2];
  const void* pos  = d_in[3];
  const void* Wq   = d_in[4];
  const void* Wk   = d_in[5];
  const void* Wv   = d_in[6];
  const void* Wo   = d_in[7];
  const void* bo   = d_in[8];
  const void* W1   = d_in[9];
  const void* b1   = d_in[10];
  const void* W2   = d_in[11];
  const void* b2   = d_in[12];
  const void* ln1g = d_in[13];
  const void* ln1b = d_in[14];
  const void* ln2g = d_in[15];
  const void* ln2b = d_in[16];
  const void* lnfg = d_in[17];
  const void* lnfb = d_in[18];
  const void* Wlm  = d_in[19];
  const void* blm  = d_in[20];

  char* ws = (char*)d_ws;
  size_t off = 0;
  auto alloc = [&](size_t bytes) { void* p = ws + off; off += (bytes + 255) & ~(size_t)255; return p; };

  bf16*  x   = (bf16*)alloc((size_t)BT * CC * 2);             // 25.2 MB (bf16 residual)
  bf16*  xn  = (bf16*)alloc((size_t)BT * CC * 2);             // 25.2 MB
  bf16*  qb  = (bf16*)alloc((size_t)BB * HH * TT * DH * 2);   // 16.8 MB x3 (contiguous)
  bf16*  kb  = (bf16*)alloc((size_t)BB * HH * TT * DH * 2);
  bf16*  vb  = (bf16*)alloc((size_t)BB * HH * TT * DH * 2);
  bf16*  att = (bf16*)alloc((size_t)BT * 256 * 2);            // 16.8 MB
  float* logits = (float*)att;  // logits scratch aliases dead att (8.5MB <= 16.8MB)
  // canonical bf16 weights
  bf16* c_tok  = (bf16*)alloc((size_t)VV * CC * 2);
  bf16* c_pos  = (bf16*)alloc((size_t)TT * CC * 2);
  bf16* wqkvT  = (bf16*)alloc((size_t)LL * 768 * CC * 2);     // B^T for fused QKV
  bf16* woT    = (bf16*)alloc((size_t)LL * CC * 256 * 2);     // B^T [C][256]
  bf16* w1T    = (bf16*)alloc((size_t)LL * FFD * CC * 2);     // B^T [FFD][C]
  bf16* w2T    = (bf16*)alloc((size_t)LL * CC * FFD * 2);     // B^T [C][FFD]
  bf16* wlmT   = (bf16*)alloc((size_t)128 * CC * 2);          // B^T [128][C], rows>=65 zero
  bf16* c_bo   = (bf16*)alloc((size_t)LL * CC * 2);
  bf16* c_b1   = (bf16*)alloc((size_t)LL * FFD * 2);
  bf16* c_b2   = (bf16*)alloc((size_t)LL * CC * 2);
  bf16* c_l1g  = (bf16*)alloc((size_t)LL * CC * 2);
  bf16* c_l1b  = (bf16*)alloc((size_t)LL * CC * 2);
  bf16* c_l2g  = (bf16*)alloc((size_t)LL * CC * 2);
  bf16* c_l2b  = (bf16*)alloc((size_t)LL * CC * 2);
  bf16* c_lfg  = (bf16*)alloc((size_t)CC * 2);
  bf16* c_lfb  = (bf16*)alloc((size_t)CC * 2);
  bf16* c_blm  = (bf16*)alloc((size_t)VV * 2);
  float* loss  = (float*)alloc(256);
  int*   flag  = (int*)alloc(256);

  // FF intermediate: full-size if ws permits, else 2-chunk aliased over q/k/v.
  size_t ff1_full_bytes = (size_t)BT * FFD * 2;               // 100.7 MB
  int    nchunks;
  int    fch;
  bf16*  ff1;
  if (ws_size - off >= ff1_full_bytes + 256) {
    ff1 = (bf16*)alloc(ff1_full_bytes);
    nchunks = 1; fch = BT;
  } else {
    ff1 = qb;
    nchunks = 2; fch = BT / 2;
  }

  hipMemsetAsync(loss, 0, 4, stream);

  detect_kernel<<<1, 256, 0, stream>>>((const unsigned short*)tok, flag);

  {
    ConvBatch cb;
    const void* srcs[NSEG] = {tok, pos, bo, b1, b2, ln1g, ln1b, ln2g, ln2b, lnfg, lnfb, blm, Wlm};
    bf16* dsts[NSEG] = {c_tok, c_pos, c_bo, c_b1, c_b2, c_l1g, c_l1b, c_l2g, c_l2b, c_lfg, c_lfb, c_blm, nullptr};
    int lens[NSEG] = {VV * CC, TT * CC, LL * CC, LL * FFD, LL * CC, LL * CC, LL * CC,
                      LL * CC, LL * CC, CC, CC, VV, 0};
    int maxlen = 0;
    for (int i = 0; i < NSEG; ++i) {
      cb.src[i] = srcs[i]; cb.dst[i] = dsts[i]; cb.len[i] = lens[i];
      if (lens[i] > maxlen) maxlen = lens[i];
    }
    convert_batch_kernel<<<dim3((maxlen + 255) / 256, NSEG), 256, 0, stream>>>(cb, flag);
  }

  {
    int tq = LL * 768 * CC;
    repack_qkvT<<<(tq + 255) / 256, 256, 0, stream>>>(Wq, Wk, Wv, wqkvT, flag);
    int t1 = LL * 256 * CC;
    transpose_w<<<(t1 + 255) / 256, 256, 0, stream>>>(Wo, woT, 256, CC, t1, flag);
    int t2 = LL * CC * FFD;
    transpose_w<<<(t2 + 255) / 256, 256, 0, stream>>>(W1, w1T, CC, FFD, t2, flag);
    transpose_w<<<(t2 + 255) / 256, 256, 0, stream>>>(W2, w2T, FFD, CC, t2, flag);
    int t3 = 128 * CC;
    repack_lmT<<<(t3 + 255) / 256, 256, 0, stream>>>(Wlm, wlmT, flag);
  }

  embed_kernel<<<BT, CC, 0, stream>>>(idx, c_tok, c_pos, x);

  for (int l = 0; l < LL; ++l) {
    ln_kernel<<<BT / 4, 256, 0, stream>>>(x, xn, c_l1g + l * CC, c_l1b + l * CC);

    // QKV: N=768 -> BN=64 tiles, grid (12,256)=3072 blocks, 3 blocks/CU
    mfma_gemm<OUT_QKV, false, 64><<<dim3(768 / 64, BT / 128), 256, 0, stream>>>(
        xn, wqkvT + (size_t)l * 768 * CC, nullptr, qb, BT, 768, CC);

    attn_mfma_kernel<<<BB * HH, 512, 0, stream>>>(qb, kb, vb, att);

    // Wo: N=384 -> BN=64 tiles, grid (6,256)=1536 blocks
    mfma_gemm<OUT_RES, false, 64><<<dim3(CC / 64, BT / 128), 256, 0, stream>>>(
        att, woT + (size_t)l * CC * 256, c_bo + l * CC, x, BT, CC, 256);

    ln_kernel<<<BT / 4, 256, 0, stream>>>(x, xn, c_l2g + l * CC, c_l2b + l * CC);

    for (int ch = 0; ch < nchunks; ++ch) {
      const bf16* Ach = xn + (size_t)ch * fch * CC;
      // FF1: N=1536 -> BN=64 tiles, grid (24,256)=6144 blocks, 3 blocks/CU
      mfma_gemm<OUT_BF16, true, 64><<<dim3(FFD / 64, fch / 128), 256, 0, stream>>>(
          Ach, w1T + (size_t)l * FFD * CC, c_b1 + l * FFD, ff1, fch, FFD, CC);
      // FF2: N=384 -> BN=64 tiles, grid (6, fch/128) = 1536 blocks
      mfma_gemm<OUT_RES, false, 64><<<dim3(CC / 64, fch / 128), 256, 0, stream>>>(
          ff1, w2T + (size_t)l * CC * FFD, c_b2 + l * CC, x + (size_t)ch * fch * CC, fch, CC, FFD);
    }
  }

  ln_kernel<<<BT / 4, 256, 0, stream>>>(x, xn, c_lfg, c_lfb);
  // LM head: [BT,384] x [384,65->128] via MFMA, BN=64 -> grid (2,256)=512
  mfma_gemm<OUT_LMH, false, 64><<<dim3(2, BT / 128), 256, 0, stream>>>(
      xn, wlmT, c_blm, logits, BT, 128, CC);
  loss_kernel<<<1024, 256, 0, stream>>>(logits, targets, d_out, loss, flag);
  finalize_kernel<<<1, 1, 0, stream>>>(loss, d_out, flag);
}

// Round 16
// 1386.254 us; speedup vs baseline: 1.0755x; 1.0354x over previous
//
#include <hip/hip_runtime.h>
#include <hip/hip_bf16.h>

typedef __hip_bfloat16 bf16;

// Problem constants
#define BB   128
#define TT   256
#define CC   384
#define HH   4
#define DH   64
#define LL   6
#define VV   65
#define FFD  1536
#define BT   (BB * TT)   // 32768

__device__ __forceinline__ float b2f(bf16 h) { return __bfloat162float(h); }
__device__ __forceinline__ bf16  f2b(float f) { return __float2bfloat16(f); }

typedef __bf16 bf16x8 __attribute__((ext_vector_type(8)));
typedef float  f32x4  __attribute__((ext_vector_type(4)));

__device__ __forceinline__ __bf16 f2n(float f) {
  bf16 h = f2b(f);
  return __builtin_bit_cast(__bf16, h);
}

// global(16B) -> LDS direct copy; LDS dest = wave-uniform base + lane*16
__device__ __forceinline__ void gld_lds16(const void* g, void* l) {
  __builtin_amdgcn_global_load_lds(
      (const __attribute__((address_space(1))) unsigned int*)(unsigned long long)g,
      (__attribute__((address_space(3))) unsigned int*)(unsigned long long)l,
      16, 0, 0);
}

// ---------------------------------------------------------------------------
// Detect input dtype: fp32 (flag=1) vs bf16 (flag=0), via tok_emb bit patterns.
// ---------------------------------------------------------------------------
__global__ __launch_bounds__(256) void detect_kernel(const unsigned short* __restrict__ tok,
                                                     int* __restrict__ flag)
{
  __shared__ int cnt;
  if (threadIdx.x == 0) cnt = 0;
  __syncthreads();
  int c = 0;
  for (int i = threadIdx.x; i < 512; i += 256) {
    int e = (tok[i] >> 7) & 0xFF;
    if (e >= 130) c++;
  }
  atomicAdd(&cnt, c);
  __syncthreads();
  if (threadIdx.x == 0) flag[0] = (cnt > 16) ? 1 : 0;
}

__device__ __forceinline__ float load_flag(const void* src, size_t i, int fl) {
  return fl ? ((const float*)src)[i] : b2f(((const bf16*)src)[i]);
}

// Batched canonicalization of all small tensors in ONE launch.
#define NSEG 13
struct ConvBatch {
  const void* src[NSEG];
  bf16*       dst[NSEG];
  int         len[NSEG];
};

__global__ __launch_bounds__(256) void convert_batch_kernel(ConvBatch cb,
                                                            const int* __restrict__ flag)
{
  int seg = blockIdx.y;
  int i = blockIdx.x * 256 + threadIdx.x;
  if (i >= cb.len[seg]) return;
  cb.dst[seg][i] = f2b(load_flag(cb.src[seg], i, flag[0]));
}

// Generic per-layer transpose: in [L][R][Cc] -> out [L][Cc][R] (bf16), coalesced out.
__global__ __launch_bounds__(256) void transpose_w(const void* __restrict__ src,
                                                   bf16* __restrict__ dst,
                                                   int R, int Cc, int total,
                                                   const int* __restrict__ flag)
{
  int o = blockIdx.x * 256 + threadIdx.x;
  if (o >= total) return;
  int i2 = o % R;
  int j  = (o / R) % Cc;
  int l  = o / (R * Cc);
  dst[o] = f2b(load_flag(src, ((size_t)(l * R + i2)) * Cc + j, flag[0]));
}

// Wlm^T padded repack: dst[n][c] (n<128) = Wlm[c][n] for n<65 else 0.
__global__ __launch_bounds__(256) void repack_lmT(const void* __restrict__ wlm,
                                                  bf16* __restrict__ dst,
                                                  const int* __restrict__ flag)
{
  int o = blockIdx.x * 256 + threadIdx.x;   // total = 128*CC
  if (o >= 128 * CC) return;
  int c = o % CC;
  int n = o / CC;
  float v = (n < VV) ? load_flag(wlm, (size_t)c * VV + n, flag[0]) : 0.f;
  dst[o] = f2b(v);
}

// Fused QKV B^T repack: dst[l][n][c] (n in 0..767) from Wq/Wk/Wv [L,H,C,HS].
__global__ __launch_bounds__(256) void repack_qkvT(const void* __restrict__ wq,
                                                   const void* __restrict__ wk,
                                                   const void* __restrict__ wv,
                                                   bf16* __restrict__ dst,
                                                   const int* __restrict__ flag)
{
  int o = blockIdx.x * 256 + threadIdx.x;   // total = LL*768*CC
  if (o >= LL * 768 * CC) return;
  int c = o % CC;
  int n = (o / CC) % 768;
  int l = o / (CC * 768);
  const void* src = (n < 256) ? wq : (n < 512) ? wk : wv;
  int h = (n >> 6) & 3, d = n & 63;
  dst[o] = f2b(load_flag(src, (((size_t)(l * HH + h)) * CC + c) * DH + d, flag[0]));
}

// ---------------------------------------------------------------------------
// Embedding: x[bt, c] = tok_emb[idx[bt], c] + pos_emb[bt % T, c]   (bf16 out)
// ---------------------------------------------------------------------------
__global__ __launch_bounds__(CC) void embed_kernel(
    const int* __restrict__ idx, const bf16* __restrict__ tok,
    const bf16* __restrict__ pos, bf16* __restrict__ x)
{
  int bt = blockIdx.x;
  int c  = threadIdx.x;
  int tok_id = idx[bt];
  int t = bt & (TT - 1);
  x[(size_t)bt * CC + c] = f2b(b2f(tok[(size_t)tok_id * CC + c]) + b2f(pos[(size_t)t * CC + c]));
}

// ---------------------------------------------------------------------------
// LayerNorm: bf16 x row -> bf16 xn row. One wave per row (C=384 -> 6/lane).
// ---------------------------------------------------------------------------
__global__ __launch_bounds__(256) void ln_kernel(
    const bf16* __restrict__ x, bf16* __restrict__ xn,
    const bf16* __restrict__ g, const bf16* __restrict__ b)
{
  int lane = threadIdx.x & 63;
  int wid  = threadIdx.x >> 6;
  int r = blockIdx.x * 4 + wid;
  const bf16* xr = x + (size_t)r * CC;
  float vals[6];
  float s = 0.f, ss = 0.f;
#pragma unroll
  for (int i = 0; i < 6; ++i) {
    float v = b2f(xr[lane + i * 64]);
    vals[i] = v; s += v; ss += v * v;
  }
#pragma unroll
  for (int off = 32; off; off >>= 1) {
    s  += __shfl_xor(s, off, 64);
    ss += __shfl_xor(ss, off, 64);
  }
  float mu   = s * (1.f / CC);
  float var  = ss * (1.f / CC) - mu * mu;
  float rstd = rsqrtf(var + 1e-5f);
  bf16* xo = xn + (size_t)r * CC;
#pragma unroll
  for (int i = 0; i < 6; ++i) {
    int c = lane + i * 64;
    xo[c] = f2b((vals[i] - mu) * rstd * b2f(g[c]) + b2f(b[c]));
  }
}

// ---------------------------------------------------------------------------
// MFMA GEMM v3 (round-10 best config): C[M,N] = A[M,K](bf16) * B^T[N,K](bf16).
// BM=128, BN template (128 or 64), BK=64, 4 waves, 2-deep double-buffered LDS
// with counted-vmcnt pipeline, bijective XCD swizzle.
//   BN=128: waves 2x2, each 64x64 (MI=4,NI=4), 64KB LDS -> 2 blocks/CU
//   BN= 64: waves 4x1, each 32x64 (MI=2,NI=4), 48KB LDS -> 3 blocks/CU
// Empirical optimum (r10 vs r11-r15): wide-N GEMMs (QKV 768, FF1 1536) use
// BN=128 (A-tile staged fewer times); narrow-N (384/128) use BN=64 (occupancy).
// OUT_RES: bf16 residual RMW (fp32 add, bf16 store; each (m,n) single-owner).
// ---------------------------------------------------------------------------
enum { OUT_BF16 = 0, OUT_QKV = 1, OUT_RES = 2, OUT_LMH = 3 };

template<int MODE, bool RELU, int BN>
__global__ __launch_bounds__(256) void mfma_gemm(
    const bf16* __restrict__ A, const bf16* __restrict__ Bt,
    const bf16* __restrict__ bias, void* __restrict__ out,
    int M, int N, int K)
{
  constexpr int MI = (BN == 128) ? 4 : 2;
  constexpr int NI = 4;
  constexpr int BSTG = (BN == 128) ? 4 : 2;   // B stage insts/wave
  __shared__ bf16 As[2][128 * 64];
  __shared__ bf16 Bs[2][BN * 64];
  const int tid  = threadIdx.x;
  const int w    = tid >> 6, lane = tid & 63;

  // bijective XCD swizzle over (x,y) grid; launch guarantees nwg % 8 == 0
  const int nbx  = gridDim.x;
  const int nwg  = nbx * gridDim.y;
  const int orig = blockIdx.y * nbx + blockIdx.x;
  const int swz  = (orig & 7) * (nwg >> 3) + (orig >> 3);
  const int m0   = (swz / nbx) * 128, n0 = (swz % nbx) * BN;

  const int wr   = (BN == 128) ? (w >> 1) * 64 : w * 32;
  const int wc   = (BN == 128) ? (w & 1) * 64 : 0;
  const int lrow = lane & 15, lk = lane >> 4;
  const int srow8 = lane >> 3, sup = lane & 7;

  const int nsteps = K / 64;
  f32x4 acc[MI][NI] = {};

  auto stage = [&](int buf, int k0) {
#pragma unroll
    for (int i = 0; i < 4; ++i) {
      int row  = w * 32 + i * 8 + srow8;
      int ulog = sup ^ (row & 7);       // pre-swizzled global source unit
      gld_lds16(A + (size_t)(m0 + row) * K + k0 + ulog * 8, &As[buf][(w * 32 + i * 8) * 64]);
    }
#pragma unroll
    for (int i = 0; i < BSTG; ++i) {
      int row  = w * (BSTG * 8) + i * 8 + srow8;
      int ulog = sup ^ (row & 7);
      gld_lds16(Bt + (size_t)(n0 + row) * K + k0 + ulog * 8, &Bs[buf][(w * (BSTG * 8) + i * 8) * 64]);
    }
  };

  stage(0, 0);   // prologue: (4+BSTG) loads in flight per wave

  for (int t = 0; t < nsteps; ++t) {
    const int cur = t & 1;
    if (t + 1 < nsteps) {
      stage(cur ^ 1, (t + 1) * 64);
      // oldest (4+BSTG) loads (buf cur) complete; newest stay in flight
      if constexpr (BN == 128) asm volatile("s_waitcnt vmcnt(8)" ::: "memory");
      else                     asm volatile("s_waitcnt vmcnt(6)" ::: "memory");
    } else {
      asm volatile("s_waitcnt vmcnt(0)" ::: "memory");
    }
    __builtin_amdgcn_s_barrier();                        // all waves: buf[cur] ready
    __builtin_amdgcn_sched_barrier(0);

    bf16x8 af[2][MI], bg[2][NI];
#pragma unroll
    for (int kk = 0; kk < 2; ++kk) {
#pragma unroll
      for (int mi = 0; mi < MI; ++mi) {
        int r = wr + mi * 16 + lrow;
        int u = (kk * 4 + lk) ^ (r & 7);                 // swizzled read
        af[kk][mi] = *reinterpret_cast<const bf16x8*>(&As[cur][r * 64 + u * 8]);
      }
#pragma unroll
      for (int ni = 0; ni < NI; ++ni) {
        int rb = wc + ni * 16 + lrow;
        int ub = (kk * 4 + lk) ^ (rb & 7);
        bg[kk][ni] = *reinterpret_cast<const bf16x8*>(&Bs[cur][rb * 64 + ub * 8]);
      }
    }
    asm volatile("s_waitcnt lgkmcnt(0)" ::: "memory");   // frags in regs
    __builtin_amdgcn_sched_barrier(0);
    __builtin_amdgcn_s_barrier();                        // buf[cur] free for reuse
    // MFMA cluster (register-only) overlaps the in-flight stage of tile t+1
#pragma unroll
    for (int kk = 0; kk < 2; ++kk)
#pragma unroll
      for (int mi = 0; mi < MI; ++mi)
#pragma unroll
        for (int ni = 0; ni < NI; ++ni)
          acc[mi][ni] = __builtin_amdgcn_mfma_f32_16x16x32_bf16(af[kk][mi], bg[kk][ni], acc[mi][ni], 0, 0, 0);
  }

  // Epilogue. D layout: col = lane&15, row = (lane>>4)*4 + r
#pragma unroll
  for (int mi = 0; mi < MI; ++mi) {
#pragma unroll
    for (int ni = 0; ni < NI; ++ni) {
#pragma unroll
      for (int r = 0; r < 4; ++r) {
        int m = m0 + wr + mi * 16 + lk * 4 + r;
        int n = n0 + wc + ni * 16 + lrow;
        float v = acc[mi][ni][r];
        if (MODE == OUT_BF16) {
          v += b2f(bias[n]);
          if (RELU) v = fmaxf(v, 0.f);
          reinterpret_cast<bf16*>(out)[(size_t)m * N + n] = f2b(v);
        } else if (MODE == OUT_RES) {
          v += b2f(bias[n]);
          bf16* xp = reinterpret_cast<bf16*>(out) + (size_t)m * N + n;
          *xp = f2b(b2f(*xp) + v);                       // bf16 residual RMW
        } else if (MODE == OUT_LMH) {
          if (n < VV)
            reinterpret_cast<float*>(out)[(size_t)m * VV + n] = v + b2f(bias[n]);
        } else {  // OUT_QKV: n<256 q, <512 k, else v; scatter to [B,H,T,DH]
          int which = n >> 8;
          int h = (n >> 6) & 3, d = n & 63;
          int b = m >> 8, trow = m & 255;
          reinterpret_cast<bf16*>(out)[(size_t)which * BB * HH * TT * DH +
              (((size_t)b * HH + h) * TT + trow) * DH + d] = f2b(v);
        }
      }
    }
  }
}

// ---------------------------------------------------------------------------
// MFMA flash attention. One block per (b,h), 512 threads (8 waves).
// ---------------------------------------------------------------------------
__global__ __launch_bounds__(512) void attn_mfma_kernel(
    const bf16* __restrict__ qg, const bf16* __restrict__ kg,
    const bf16* __restrict__ vg, bf16* __restrict__ att)
{
  __shared__ __bf16 stage[128 * 64];        // 16KB: K chunk or Vt chunk
  __shared__ __bf16 Pbuf[8][16 * 128];      // 32KB: per-wave P staging
  const int bh = blockIdx.x;
  const int b  = bh >> 2, h = bh & 3;       // H = 4
  const int tid = threadIdx.x, w = tid >> 6, lane = tid & 63;
  const int l15 = lane & 15, lk = lane >> 4;
  const bf16* Qg = qg + (size_t)bh * TT * DH;
  const bf16* Kg = kg + (size_t)bh * TT * DH;
  const bf16* Vg = vg + (size_t)bh * TT * DH;
  __bf16* Pw = &Pbuf[w][0];

  for (int qp = 0; qp < 2; ++qp) {
    const int qt = qp ? (15 - w) : w;
    const int mrow0 = qt * 16 + lk * 4;

    bf16x8 aq[2];
#pragma unroll
    for (int kk = 0; kk < 2; ++kk)
      aq[kk] = *reinterpret_cast<const bf16x8*>(Qg + (size_t)(qt * 16 + l15) * DH + (kk * 4 + lk) * 8);

    f32x4 sc[16];
#pragma unroll
    for (int ct = 0; ct < 16; ++ct) sc[ct] = (f32x4){0.f, 0.f, 0.f, 0.f};

    // ---- S = Q K^T over two K chunks of 128 rows ----
#pragma unroll
    for (int c = 0; c < 2; ++c) {
      {
        int rl = w * 16;
#pragma unroll
        for (int i = 0; i < 2; ++i) {
          int row  = rl + i * 8 + (lane >> 3);
          int ulog = (lane & 7) ^ (row & 7);
          gld_lds16(Kg + (size_t)(c * 128 + row) * DH + ulog * 8, &stage[(rl + i * 8) * DH]);
        }
      }
      __syncthreads();
#pragma unroll
      for (int ctl = 0; ctl < 8; ++ctl) {
        int srow = ctl * 16 + l15;
        int ct = c * 8 + ctl;
#pragma unroll
        for (int kk = 0; kk < 2; ++kk) {
          bf16x8 kf = *reinterpret_cast<const bf16x8*>(
              &stage[srow * DH + (((kk * 4 + lk) ^ (srow & 7)) * 8)]);
          sc[ct] = __builtin_amdgcn_mfma_f32_16x16x32_bf16(aq[kk], kf, sc[ct], 0, 0, 0);
        }
      }
      __syncthreads();
    }

    // ---- softmax (registers only) ----
    float mr[4] = {-1e30f, -1e30f, -1e30f, -1e30f};
#pragma unroll
    for (int ct = 0; ct < 16; ++ct) {
      int s = ct * 16 + l15;
#pragma unroll
      for (int r = 0; r < 4; ++r) {
        float v = sc[ct][r] * 0.125f;
        if (s > mrow0 + r) v = -1e30f;
        sc[ct][r] = v;
        mr[r] = fmaxf(mr[r], v);
      }
    }
#pragma unroll
    for (int off = 8; off; off >>= 1)
#pragma unroll
      for (int r = 0; r < 4; ++r) mr[r] = fmaxf(mr[r], __shfl_xor(mr[r], off, 64));
    float dsum[4] = {0.f, 0.f, 0.f, 0.f};
#pragma unroll
    for (int ct = 0; ct < 16; ++ct)
#pragma unroll
      for (int r = 0; r < 4; ++r) {
        float e = __expf(sc[ct][r] - mr[r]);
        sc[ct][r] = e;
        dsum[r] += e;
      }
#pragma unroll
    for (int off = 8; off; off >>= 1)
#pragma unroll
      for (int r = 0; r < 4; ++r) dsum[r] += __shfl_xor(dsum[r], off, 64);
    float rd[4];
#pragma unroll
    for (int r = 0; r < 4; ++r) rd[r] = 1.f / dsum[r];

    // ---- O = P V over two V chunks of 128 keys ----
    f32x4 o[4];
#pragma unroll
    for (int nt = 0; nt < 4; ++nt) o[nt] = (f32x4){0.f, 0.f, 0.f, 0.f};

#pragma unroll
    for (int c = 0; c < 2; ++c) {
      {
        int d0 = w * 8;
#pragma unroll
        for (int it = 0; it < 2; ++it) {
          int sl = it * 64 + lane;
          bf16x8 vv = *reinterpret_cast<const bf16x8*>(Vg + (size_t)(c * 128 + sl) * DH + d0);
#pragma unroll
          for (int j = 0; j < 8; ++j) {
            int u = (sl >> 3) ^ j;
            stage[(d0 + j) * 128 + u * 8 + (sl & 7)] = vv[j];
          }
        }
      }
      __syncthreads();
#pragma unroll
      for (int ctl = 0; ctl < 8; ++ctl) {
        int sl = ctl * 16 + l15;
        int u  = sl >> 3;
#pragma unroll
        for (int r = 0; r < 4; ++r) {
          int row = lk * 4 + r;
          Pw[row * 128 + ((u ^ (row & 7)) * 8) + (sl & 7)] = f2n(sc[c * 8 + ctl][r]);
        }
      }
#pragma unroll
      for (int ks = 0; ks < 4; ++ks) {
        bf16x8 pf = *reinterpret_cast<const bf16x8*>(
            &Pw[l15 * 128 + (((ks * 4 + lk) ^ (l15 & 7)) * 8)]);
#pragma unroll
        for (int nt = 0; nt < 4; ++nt) {
          int dd = nt * 16 + l15;
          bf16x8 vf = *reinterpret_cast<const bf16x8*>(
              &stage[dd * 128 + (((ks * 4 + lk) ^ (dd & 7)) * 8)]);
          o[nt] = __builtin_amdgcn_mfma_f32_16x16x32_bf16(pf, vf, o[nt], 0, 0, 0);
        }
      }
      __syncthreads();
    }

#pragma unroll
    for (int nt = 0; nt < 4; ++nt)
#pragma unroll
      for (int r = 0; r < 4; ++r) {
        int t = qt * 16 + lk * 4 + r;
        int d = nt * 16 + l15;
        att[(((size_t)b * TT + t) * HH + h) * DH + d] = f2b(o[nt][r] * rd[r]);
      }
    __syncthreads();
  }
}

// ---------------------------------------------------------------------------
// Loss + d_out write from fp32 logits scratch. 1024 blocks x 4 waves; each
// wave handles 8 rows; ONE atomic per block.
// ---------------------------------------------------------------------------
__global__ __launch_bounds__(256) void loss_kernel(
    const float* __restrict__ logits, const int* __restrict__ targets,
    void* __restrict__ out, float* __restrict__ loss,
    const int* __restrict__ flag)
{
  __shared__ float wsums[4];
  int wid = threadIdx.x >> 6, lane = threadIdx.x & 63;
  int fl = flag[0];
  float wacc = 0.f;

  for (int i = 0; i < 8; ++i) {
    int r = (blockIdx.x * 4 + wid) * 8 + i;
    const float* lr = logits + (size_t)r * VV;
    float a0 = lr[lane];
    float a1 = (lane == 0) ? lr[64] : -1e30f;

    if (fl) {
      float* o = (float*)out;
      o[(size_t)r * VV + lane] = a0;
      if (lane == 0) o[(size_t)r * VV + 64] = a1;
    } else {
      bf16* o = (bf16*)out;
      o[(size_t)r * VV + lane] = f2b(a0);
      if (lane == 0) o[(size_t)r * VV + 64] = f2b(a1);
    }

    float m = fmaxf(a0, a1);
#pragma unroll
    for (int off = 32; off; off >>= 1) m = fmaxf(m, __shfl_xor(m, off, 64));
    float e = __expf(a0 - m) + ((lane == 0) ? __expf(a1 - m) : 0.f);
#pragma unroll
    for (int off = 32; off; off >>= 1) e += __shfl_xor(e, off, 64);
    float logZ = m + logf(e);
    int tgt = targets[r];
    float contrib = (lane == tgt) ? (a0 - logZ) : 0.f;
    if (lane == 0 && tgt == 64) contrib = a1 - logZ;
#pragma unroll
    for (int off = 32; off; off >>= 1) contrib += __shfl_xor(contrib, off, 64);
    wacc += contrib;
  }

  if (lane == 0) wsums[wid] = wacc;
  __syncthreads();
  if (threadIdx.x == 0)
    atomicAdd(loss, -(wsums[0] + wsums[1] + wsums[2] + wsums[3]));
}

__global__ void finalize_kernel(const float* __restrict__ loss, void* __restrict__ out,
                                const int* __restrict__ flag)
{
  float v = loss[0] * (1.f / BT);
  if (flag[0]) ((float*)out)[(size_t)BT * VV] = v;
  else         ((bf16*)out)[(size_t)BT * VV]  = f2b(v);
}

// ---------------------------------------------------------------------------
extern "C" void kernel_launch(void* const* d_in, const int* in_sizes, int n_in,
                              void* d_out, int out_size, void* d_ws, size_t ws_size,
                              hipStream_t stream)
{
  const int* idx     = (const int*)d_in[0];
  const int* targets = (const int*)d_in[1];
  const void* tok  = d_in[2];
  const void* pos  = d_in[3];
  const void* Wq   = d_in[4];
  const void* Wk   = d_in[5];
  const void* Wv   = d_in[6];
  const void* Wo   = d_in[7];
  const void* bo   = d_in[8];
  const void* W1   = d_in[9];
  const void* b1   = d_in[10];
  const void* W2   = d_in[11];
  const void* b2   = d_in[12];
  const void* ln1g = d_in[13];
  const void* ln1b = d_in[14];
  const void* ln2g = d_in[15];
  const void* ln2b = d_in[16];
  const void* lnfg = d_in[17];
  const void* lnfb = d_in[18];
  const void* Wlm  = d_in[19];
  const void* blm  = d_in[20];

  char* ws = (char*)d_ws;
  size_t off = 0;
  auto alloc = [&](size_t bytes) { void* p = ws + off; off += (bytes + 255) & ~(size_t)255; return p; };

  bf16*  x   = (bf16*)alloc((size_t)BT * CC * 2);             // 25.2 MB (bf16 residual)
  bf16*  xn  = (bf16*)alloc((size_t)BT * CC * 2);             // 25.2 MB
  bf16*  qb  = (bf16*)alloc((size_t)BB * HH * TT * DH * 2);   // 16.8 MB x3 (contiguous)
  bf16*  kb  = (bf16*)alloc((size_t)BB * HH * TT * DH * 2);
  bf16*  vb  = (bf16*)alloc((size_t)BB * HH * TT * DH * 2);
  bf16*  att = (bf16*)alloc((size_t)BT * 256 * 2);            // 16.8 MB
  float* logits = (float*)att;  // logits scratch aliases dead att (8.5MB <= 16.8MB)
  // canonical bf16 weights
  bf16* c_tok  = (bf16*)alloc((size_t)VV * CC * 2);
  bf16* c_pos  = (bf16*)alloc((size_t)TT * CC * 2);
  bf16* wqkvT  = (bf16*)alloc((size_t)LL * 768 * CC * 2);     // B^T for fused QKV
  bf16* woT    = (bf16*)alloc((size_t)LL * CC * 256 * 2);     // B^T [C][256]
  bf16* w1T    = (bf16*)alloc((size_t)LL * FFD * CC * 2);     // B^T [FFD][C]
  bf16* w2T    = (bf16*)alloc((size_t)LL * CC * FFD * 2);     // B^T [C][FFD]
  bf16* wlmT   = (bf16*)alloc((size_t)128 * CC * 2);          // B^T [128][C], rows>=65 zero
  bf16* c_bo   = (bf16*)alloc((size_t)LL * CC * 2);
  bf16* c_b1   = (bf16*)alloc((size_t)LL * FFD * 2);
  bf16* c_b2   = (bf16*)alloc((size_t)LL * CC * 2);
  bf16* c_l1g  = (bf16*)alloc((size_t)LL * CC * 2);
  bf16* c_l1b  = (bf16*)alloc((size_t)LL * CC * 2);
  bf16* c_l2g  = (bf16*)alloc((size_t)LL * CC * 2);
  bf16* c_l2b  = (bf16*)alloc((size_t)LL * CC * 2);
  bf16* c_lfg  = (bf16*)alloc((size_t)CC * 2);
  bf16* c_lfb  = (bf16*)alloc((size_t)CC * 2);
  bf16* c_blm  = (bf16*)alloc((size_t)VV * 2);
  float* loss  = (float*)alloc(256);
  int*   flag  = (int*)alloc(256);

  // FF intermediate: full-size if ws permits, else 2-chunk aliased over q/k/v.
  size_t ff1_full_bytes = (size_t)BT * FFD * 2;               // 100.7 MB
  int    nchunks;
  int    fch;
  bf16*  ff1;
  if (ws_size - off >= ff1_full_bytes + 256) {
    ff1 = (bf16*)alloc(ff1_full_bytes);
    nchunks = 1; fch = BT;
  } else {
    ff1 = qb;
    nchunks = 2; fch = BT / 2;
  }

  hipMemsetAsync(loss, 0, 4, stream);

  detect_kernel<<<1, 256, 0, stream>>>((const unsigned short*)tok, flag);

  {
    ConvBatch cb;
    const void* srcs[NSEG] = {tok, pos, bo, b1, b2, ln1g, ln1b, ln2g, ln2b, lnfg, lnfb, blm, Wlm};
    bf16* dsts[NSEG] = {c_tok, c_pos, c_bo, c_b1, c_b2, c_l1g, c_l1b, c_l2g, c_l2b, c_lfg, c_lfb, c_blm, nullptr};
    int lens[NSEG] = {VV * CC, TT * CC, LL * CC, LL * FFD, LL * CC, LL * CC, LL * CC,
                      LL * CC, LL * CC, CC, CC, VV, 0};
    int maxlen = 0;
    for (int i = 0; i < NSEG; ++i) {
      cb.src[i] = srcs[i]; cb.dst[i] = dsts[i]; cb.len[i] = lens[i];
      if (lens[i] > maxlen) maxlen = lens[i];
    }
    convert_batch_kernel<<<dim3((maxlen + 255) / 256, NSEG), 256, 0, stream>>>(cb, flag);
  }

  {
    int tq = LL * 768 * CC;
    repack_qkvT<<<(tq + 255) / 256, 256, 0, stream>>>(Wq, Wk, Wv, wqkvT, flag);
    int t1 = LL * 256 * CC;
    transpose_w<<<(t1 + 255) / 256, 256, 0, stream>>>(Wo, woT, 256, CC, t1, flag);
    int t2 = LL * CC * FFD;
    transpose_w<<<(t2 + 255) / 256, 256, 0, stream>>>(W1, w1T, CC, FFD, t2, flag);
    transpose_w<<<(t2 + 255) / 256, 256, 0, stream>>>(W2, w2T, FFD, CC, t2, flag);
    int t3 = 128 * CC;
    repack_lmT<<<(t3 + 255) / 256, 256, 0, stream>>>(Wlm, wlmT, flag);
  }

  embed_kernel<<<BT, CC, 0, stream>>>(idx, c_tok, c_pos, x);

  for (int l = 0; l < LL; ++l) {
    ln_kernel<<<BT / 4, 256, 0, stream>>>(x, xn, c_l1g + l * CC, c_l1b + l * CC);

    // QKV: N=768 -> BN=128 tiles, grid (6,256)=1536 blocks
    mfma_gemm<OUT_QKV, false, 128><<<dim3(768 / 128, BT / 128), 256, 0, stream>>>(
        xn, wqkvT + (size_t)l * 768 * CC, nullptr, qb, BT, 768, CC);

    attn_mfma_kernel<<<BB * HH, 512, 0, stream>>>(qb, kb, vb, att);

    // Wo: N=384 -> BN=64 tiles, grid (6,256)=1536 blocks
    mfma_gemm<OUT_RES, false, 64><<<dim3(CC / 64, BT / 128), 256, 0, stream>>>(
        att, woT + (size_t)l * CC * 256, c_bo + l * CC, x, BT, CC, 256);

    ln_kernel<<<BT / 4, 256, 0, stream>>>(x, xn, c_l2g + l * CC, c_l2b + l * CC);

    for (int ch = 0; ch < nchunks; ++ch) {
      const bf16* Ach = xn + (size_t)ch * fch * CC;
      // FF1: N=1536 -> BN=128 tiles, grid (12,256)=3072 blocks
      mfma_gemm<OUT_BF16, true, 128><<<dim3(FFD / 128, fch / 128), 256, 0, stream>>>(
          Ach, w1T + (size_t)l * FFD * CC, c_b1 + l * FFD, ff1, fch, FFD, CC);
      // FF2: N=384 -> BN=64 tiles, grid (6, fch/128) = 1536 blocks
      mfma_gemm<OUT_RES, false, 64><<<dim3(CC / 64, fch / 128), 256, 0, stream>>>(
          ff1, w2T + (size_t)l * CC * FFD, c_b2 + l * CC, x + (size_t)ch * fch * CC, fch, CC, FFD);
    }
  }

  ln_kernel<<<BT / 4, 256, 0, stream>>>(x, xn, c_lfg, c_lfb);
  // LM head: [BT,384] x [384,65->128] via MFMA, BN=64 -> grid (2,256)=512
  mfma_gemm<OUT_LMH, false, 64><<<dim3(2, BT / 128), 256, 0, stream>>>(
      xn, wlmT, c_blm, logits, BT, 128, CC);
  loss_kernel<<<1024, 256, 0, stream>>>(logits, targets, d_out, loss, flag);
  finalize_kernel<<<1, 1, 0, stream>>>(loss, d_out, flag);
}

// Round 17
// 1364.326 us; speedup vs baseline: 1.0928x; 1.0161x over previous
//
#include <hip/hip_runtime.h>
#include <hip/hip_bf16.h>

typedef __hip_bfloat16 bf16;

// Problem constants
#define BB   128
#define TT   256
#define CC   384
#define HH   4
#define DH   64
#define LL   6
#define VV   65
#define FFD  1536
#define BT   (BB * TT)   // 32768

__device__ __forceinline__ float b2f(bf16 h) { return __bfloat162float(h); }
__device__ __forceinline__ bf16  f2b(float f) { return __float2bfloat16(f); }

typedef __bf16 bf16x8 __attribute__((ext_vector_type(8)));
typedef float  f32x4  __attribute__((ext_vector_type(4)));

__device__ __forceinline__ __bf16 f2n(float f) {
  bf16 h = f2b(f);
  return __builtin_bit_cast(__bf16, h);
}

// global(16B) -> LDS direct copy; LDS dest = wave-uniform base + lane*16
__device__ __forceinline__ void gld_lds16(const void* g, void* l) {
  __builtin_amdgcn_global_load_lds(
      (const __attribute__((address_space(1))) unsigned int*)(unsigned long long)g,
      (__attribute__((address_space(3))) unsigned int*)(unsigned long long)l,
      16, 0, 0);
}

// ---------------------------------------------------------------------------
// Detect input dtype: fp32 (flag=1) vs bf16 (flag=0), via tok_emb bit patterns.
// ---------------------------------------------------------------------------
__global__ __launch_bounds__(256) void detect_kernel(const unsigned short* __restrict__ tok,
                                                     int* __restrict__ flag)
{
  __shared__ int cnt;
  if (threadIdx.x == 0) cnt = 0;
  __syncthreads();
  int c = 0;
  for (int i = threadIdx.x; i < 512; i += 256) {
    int e = (tok[i] >> 7) & 0xFF;
    if (e >= 130) c++;
  }
  atomicAdd(&cnt, c);
  __syncthreads();
  if (threadIdx.x == 0) flag[0] = (cnt > 16) ? 1 : 0;
}

__device__ __forceinline__ float load_flag(const void* src, size_t i, int fl) {
  return fl ? ((const float*)src)[i] : b2f(((const bf16*)src)[i]);
}

// Batched canonicalization of all small tensors in ONE launch.
#define NSEG 12
struct ConvBatch {
  const void* src[NSEG];
  bf16*       dst[NSEG];
  int         len[NSEG];
};

__global__ __launch_bounds__(256) void convert_batch_kernel(ConvBatch cb,
                                                            const int* __restrict__ flag)
{
  int seg = blockIdx.y;
  int i = blockIdx.x * 256 + threadIdx.x;
  if (i >= cb.len[seg]) return;
  cb.dst[seg][i] = f2b(load_flag(cb.src[seg], i, flag[0]));
}

// ---------------------------------------------------------------------------
// Merged weight prep: Wo/W1/W2 transposes + padded Wlm^T in ONE launch.
// ---------------------------------------------------------------------------
#define T1 (LL * 256 * CC)
#define T2 (LL * CC * FFD)
#define T3 (128 * CC)

__global__ __launch_bounds__(256) void prep_weights(
    const void* __restrict__ Wo, const void* __restrict__ W1,
    const void* __restrict__ W2, const void* __restrict__ wlm,
    bf16* __restrict__ woT, bf16* __restrict__ w1T,
    bf16* __restrict__ w2T, bf16* __restrict__ wlmT,
    const int* __restrict__ flag)
{
  int o = blockIdx.x * 256 + threadIdx.x;
  int fl = flag[0];
  if (o < T1) {                                  // Wo [L][256][CC] -> [L][CC][256]
    int i2 = o % 256, j = (o / 256) % CC, l = o / (256 * CC);
    woT[o] = f2b(load_flag(Wo, ((size_t)(l * 256 + i2)) * CC + j, fl));
    return;
  }
  o -= T1;
  if (o < T2) {                                  // W1 [L][CC][FFD] -> [L][FFD][CC]
    int i2 = o % CC, j = (o / CC) % FFD, l = o / (CC * FFD);
    w1T[o] = f2b(load_flag(W1, ((size_t)(l * CC + i2)) * FFD + j, fl));
    return;
  }
  o -= T2;
  if (o < T2) {                                  // W2 [L][FFD][CC] -> [L][CC][FFD]
    int i2 = o % FFD, j = (o / FFD) % CC, l = o / (FFD * CC);
    w2T[o] = f2b(load_flag(W2, ((size_t)(l * FFD + i2)) * CC + j, fl));
    return;
  }
  o -= T2;
  if (o < T3) {                                  // Wlm [CC][VV] -> [128][CC], pad 0
    int c = o % CC, n = o / CC;
    wlmT[o] = f2b((n < VV) ? load_flag(wlm, (size_t)c * VV + n, fl) : 0.f);
  }
}

// Fused QKV B^T repack: dst[l][n][c] (n in 0..767) from Wq/Wk/Wv [L,H,C,HS].
__global__ __launch_bounds__(256) void repack_qkvT(const void* __restrict__ wq,
                                                   const void* __restrict__ wk,
                                                   const void* __restrict__ wv,
                                                   bf16* __restrict__ dst,
                                                   const int* __restrict__ flag)
{
  int o = blockIdx.x * 256 + threadIdx.x;   // total = LL*768*CC
  if (o >= LL * 768 * CC) return;
  int c = o % CC;
  int n = (o / CC) % 768;
  int l = o / (CC * 768);
  const void* src = (n < 256) ? wq : (n < 512) ? wk : wv;
  int h = (n >> 6) & 3, d = n & 63;
  dst[o] = f2b(load_flag(src, (((size_t)(l * HH + h)) * CC + c) * DH + d, flag[0]));
}

// ---------------------------------------------------------------------------
// Embedding (vectorized bf16x8): x[bt,c8] = tok[idx[bt],c8] + pos[bt%T,c8]
// ---------------------------------------------------------------------------
__global__ __launch_bounds__(256) void embed_kernel(
    const int* __restrict__ idx, const bf16* __restrict__ tok,
    const bf16* __restrict__ pos, bf16* __restrict__ x)
{
  int i = blockIdx.x * 256 + threadIdx.x;       // i < BT * 48
  if (i >= BT * 48) return;
  int bt = i / 48, c8 = (i - bt * 48) * 8;
  int t = bt & (TT - 1);
  bf16x8 a = *reinterpret_cast<const bf16x8*>(tok + (size_t)idx[bt] * CC + c8);
  bf16x8 p = *reinterpret_cast<const bf16x8*>(pos + (size_t)t * CC + c8);
  bf16x8 o;
#pragma unroll
  for (int j = 0; j < 8; ++j) o[j] = f2n((float)a[j] + (float)p[j]);
  *reinterpret_cast<bf16x8*>(x + (size_t)bt * CC + c8) = o;
}

// ---------------------------------------------------------------------------
// LayerNorm (vectorized): one wave per row; lanes 0..47 hold bf16x8 each.
// ---------------------------------------------------------------------------
__global__ __launch_bounds__(256) void ln_kernel(
    const bf16* __restrict__ x, bf16* __restrict__ xn,
    const bf16* __restrict__ g, const bf16* __restrict__ b)
{
  int lane = threadIdx.x & 63;
  int wid  = threadIdx.x >> 6;
  int r = blockIdx.x * 4 + wid;
  const bf16* xr = x + (size_t)r * CC;
  bool act = lane < 48;                          // 48 * 8 = 384 = CC
  float v[8];
  float s = 0.f, ss = 0.f;
  if (act) {
    bf16x8 u = *reinterpret_cast<const bf16x8*>(xr + lane * 8);
#pragma unroll
    for (int i = 0; i < 8; ++i) {
      v[i] = (float)u[i]; s += v[i]; ss += v[i] * v[i];
    }
  }
#pragma unroll
  for (int off = 32; off; off >>= 1) {
    s  += __shfl_xor(s, off, 64);
    ss += __shfl_xor(ss, off, 64);
  }
  float mu   = s * (1.f / CC);
  float var  = ss * (1.f / CC) - mu * mu;
  float rstd = rsqrtf(var + 1e-5f);
  if (act) {
    bf16x8 gg = *reinterpret_cast<const bf16x8*>(g + lane * 8);
    bf16x8 bb = *reinterpret_cast<const bf16x8*>(b + lane * 8);
    bf16x8 o;
#pragma unroll
    for (int i = 0; i < 8; ++i)
      o[i] = f2n((v[i] - mu) * rstd * (float)gg[i] + (float)bb[i]);
    *reinterpret_cast<bf16x8*>(xn + (size_t)r * CC + lane * 8) = o;
  }
}

// ---------------------------------------------------------------------------
// MFMA GEMM v3 (round-10 best config): C[M,N] = A[M,K](bf16) * B^T[N,K](bf16).
// BM=128, BN template (128 or 64), BK=64, 4 waves, 2-deep double-buffered LDS
// with counted-vmcnt pipeline, bijective XCD swizzle.
//   BN=128: waves 2x2, each 64x64 (MI=4,NI=4), 64KB LDS -> 2 blocks/CU
//   BN= 64: waves 4x1, each 32x64 (MI=2,NI=4), 48KB LDS -> 3 blocks/CU
// Empirical optimum (r10 vs r11-r15): wide-N GEMMs (QKV 768, FF1 1536) use
// BN=128 (A-tile staged fewer times); narrow-N (384/128) use BN=64 (occupancy).
// OUT_RES: bf16 residual RMW (fp32 add, bf16 store; each (m,n) single-owner).
// ---------------------------------------------------------------------------
enum { OUT_BF16 = 0, OUT_QKV = 1, OUT_RES = 2, OUT_LMH = 3 };

template<int MODE, bool RELU, int BN>
__global__ __launch_bounds__(256) void mfma_gemm(
    const bf16* __restrict__ A, const bf16* __restrict__ Bt,
    const bf16* __restrict__ bias, void* __restrict__ out,
    int M, int N, int K)
{
  constexpr int MI = (BN == 128) ? 4 : 2;
  constexpr int NI = 4;
  constexpr int BSTG = (BN == 128) ? 4 : 2;   // B stage insts/wave
  __shared__ bf16 As[2][128 * 64];
  __shared__ bf16 Bs[2][BN * 64];
  const int tid  = threadIdx.x;
  const int w    = tid >> 6, lane = tid & 63;

  // bijective XCD swizzle over (x,y) grid; launch guarantees nwg % 8 == 0
  const int nbx  = gridDim.x;
  const int nwg  = nbx * gridDim.y;
  const int orig = blockIdx.y * nbx + blockIdx.x;
  const int swz  = (orig & 7) * (nwg >> 3) + (orig >> 3);
  const int m0   = (swz / nbx) * 128, n0 = (swz % nbx) * BN;

  const int wr   = (BN == 128) ? (w >> 1) * 64 : w * 32;
  const int wc   = (BN == 128) ? (w & 1) * 64 : 0;
  const int lrow = lane & 15, lk = lane >> 4;
  const int srow8 = lane >> 3, sup = lane & 7;

  const int nsteps = K / 64;
  f32x4 acc[MI][NI] = {};

  auto stage = [&](int buf, int k0) {
#pragma unroll
    for (int i = 0; i < 4; ++i) {
      int row  = w * 32 + i * 8 + srow8;
      int ulog = sup ^ (row & 7);       // pre-swizzled global source unit
      gld_lds16(A + (size_t)(m0 + row) * K + k0 + ulog * 8, &As[buf][(w * 32 + i * 8) * 64]);
    }
#pragma unroll
    for (int i = 0; i < BSTG; ++i) {
      int row  = w * (BSTG * 8) + i * 8 + srow8;
      int ulog = sup ^ (row & 7);
      gld_lds16(Bt + (size_t)(n0 + row) * K + k0 + ulog * 8, &Bs[buf][(w * (BSTG * 8) + i * 8) * 64]);
    }
  };

  stage(0, 0);   // prologue: (4+BSTG) loads in flight per wave

  for (int t = 0; t < nsteps; ++t) {
    const int cur = t & 1;
    if (t + 1 < nsteps) {
      stage(cur ^ 1, (t + 1) * 64);
      // oldest (4+BSTG) loads (buf cur) complete; newest stay in flight
      if constexpr (BN == 128) asm volatile("s_waitcnt vmcnt(8)" ::: "memory");
      else                     asm volatile("s_waitcnt vmcnt(6)" ::: "memory");
    } else {
      asm volatile("s_waitcnt vmcnt(0)" ::: "memory");
    }
    __builtin_amdgcn_s_barrier();                        // all waves: buf[cur] ready
    __builtin_amdgcn_sched_barrier(0);

    bf16x8 af[2][MI], bg[2][NI];
#pragma unroll
    for (int kk = 0; kk < 2; ++kk) {
#pragma unroll
      for (int mi = 0; mi < MI; ++mi) {
        int r = wr + mi * 16 + lrow;
        int u = (kk * 4 + lk) ^ (r & 7);                 // swizzled read
        af[kk][mi] = *reinterpret_cast<const bf16x8*>(&As[cur][r * 64 + u * 8]);
      }
#pragma unroll
      for (int ni = 0; ni < NI; ++ni) {
        int rb = wc + ni * 16 + lrow;
        int ub = (kk * 4 + lk) ^ (rb & 7);
        bg[kk][ni] = *reinterpret_cast<const bf16x8*>(&Bs[cur][rb * 64 + ub * 8]);
      }
    }
    asm volatile("s_waitcnt lgkmcnt(0)" ::: "memory");   // frags in regs
    __builtin_amdgcn_sched_barrier(0);
    __builtin_amdgcn_s_barrier();                        // buf[cur] free for reuse
    // MFMA cluster (register-only) overlaps the in-flight stage of tile t+1
#pragma unroll
    for (int kk = 0; kk < 2; ++kk)
#pragma unroll
      for (int mi = 0; mi < MI; ++mi)
#pragma unroll
        for (int ni = 0; ni < NI; ++ni)
          acc[mi][ni] = __builtin_amdgcn_mfma_f32_16x16x32_bf16(af[kk][mi], bg[kk][ni], acc[mi][ni], 0, 0, 0);
  }

  // Epilogue. D layout: col = lane&15, row = (lane>>4)*4 + r
#pragma unroll
  for (int mi = 0; mi < MI; ++mi) {
#pragma unroll
    for (int ni = 0; ni < NI; ++ni) {
#pragma unroll
      for (int r = 0; r < 4; ++r) {
        int m = m0 + wr + mi * 16 + lk * 4 + r;
        int n = n0 + wc + ni * 16 + lrow;
        float v = acc[mi][ni][r];
        if (MODE == OUT_BF16) {
          v += b2f(bias[n]);
          if (RELU) v = fmaxf(v, 0.f);
          reinterpret_cast<bf16*>(out)[(size_t)m * N + n] = f2b(v);
        } else if (MODE == OUT_RES) {
          v += b2f(bias[n]);
          bf16* xp = reinterpret_cast<bf16*>(out) + (size_t)m * N + n;
          *xp = f2b(b2f(*xp) + v);                       // bf16 residual RMW
        } else if (MODE == OUT_LMH) {
          if (n < VV)
            reinterpret_cast<float*>(out)[(size_t)m * VV + n] = v + b2f(bias[n]);
        } else {  // OUT_QKV: n<256 q, <512 k, else v; scatter to [B,H,T,DH]
          int which = n >> 8;
          int h = (n >> 6) & 3, d = n & 63;
          int b = m >> 8, trow = m & 255;
          reinterpret_cast<bf16*>(out)[(size_t)which * BB * HH * TT * DH +
              (((size_t)b * HH + h) * TT + trow) * DH + d] = f2b(v);
        }
      }
    }
  }
}

// ---------------------------------------------------------------------------
// MFMA flash attention. One block per (b,h), 512 threads (8 waves).
// ---------------------------------------------------------------------------
__global__ __launch_bounds__(512) void attn_mfma_kernel(
    const bf16* __restrict__ qg, const bf16* __restrict__ kg,
    const bf16* __restrict__ vg, bf16* __restrict__ att)
{
  __shared__ __bf16 stage[128 * 64];        // 16KB: K chunk or Vt chunk
  __shared__ __bf16 Pbuf[8][16 * 128];      // 32KB: per-wave P staging
  const int bh = blockIdx.x;
  const int b  = bh >> 2, h = bh & 3;       // H = 4
  const int tid = threadIdx.x, w = tid >> 6, lane = tid & 63;
  const int l15 = lane & 15, lk = lane >> 4;
  const bf16* Qg = qg + (size_t)bh * TT * DH;
  const bf16* Kg = kg + (size_t)bh * TT * DH;
  const bf16* Vg = vg + (size_t)bh * TT * DH;
  __bf16* Pw = &Pbuf[w][0];

  for (int qp = 0; qp < 2; ++qp) {
    const int qt = qp ? (15 - w) : w;
    const int mrow0 = qt * 16 + lk * 4;

    bf16x8 aq[2];
#pragma unroll
    for (int kk = 0; kk < 2; ++kk)
      aq[kk] = *reinterpret_cast<const bf16x8*>(Qg + (size_t)(qt * 16 + l15) * DH + (kk * 4 + lk) * 8);

    f32x4 sc[16];
#pragma unroll
    for (int ct = 0; ct < 16; ++ct) sc[ct] = (f32x4){0.f, 0.f, 0.f, 0.f};

    // ---- S = Q K^T over two K chunks of 128 rows ----
#pragma unroll
    for (int c = 0; c < 2; ++c) {
      {
        int rl = w * 16;
#pragma unroll
        for (int i = 0; i < 2; ++i) {
          int row  = rl + i * 8 + (lane >> 3);
          int ulog = (lane & 7) ^ (row & 7);
          gld_lds16(Kg + (size_t)(c * 128 + row) * DH + ulog * 8, &stage[(rl + i * 8) * DH]);
        }
      }
      __syncthreads();
#pragma unroll
      for (int ctl = 0; ctl < 8; ++ctl) {
        int srow = ctl * 16 + l15;
        int ct = c * 8 + ctl;
#pragma unroll
        for (int kk = 0; kk < 2; ++kk) {
          bf16x8 kf = *reinterpret_cast<const bf16x8*>(
              &stage[srow * DH + (((kk * 4 + lk) ^ (srow & 7)) * 8)]);
          sc[ct] = __builtin_amdgcn_mfma_f32_16x16x32_bf16(aq[kk], kf, sc[ct], 0, 0, 0);
        }
      }
      __syncthreads();
    }

    // ---- softmax (registers only) ----
    float mr[4] = {-1e30f, -1e30f, -1e30f, -1e30f};
#pragma unroll
    for (int ct = 0; ct < 16; ++ct) {
      int s = ct * 16 + l15;
#pragma unroll
      for (int r = 0; r < 4; ++r) {
        float v = sc[ct][r] * 0.125f;
        if (s > mrow0 + r) v = -1e30f;
        sc[ct][r] = v;
        mr[r] = fmaxf(mr[r], v);
      }
    }
#pragma unroll
    for (int off = 8; off; off >>= 1)
#pragma unroll
      for (int r = 0; r < 4; ++r) mr[r] = fmaxf(mr[r], __shfl_xor(mr[r], off, 64));
    float dsum[4] = {0.f, 0.f, 0.f, 0.f};
#pragma unroll
    for (int ct = 0; ct < 16; ++ct)
#pragma unroll
      for (int r = 0; r < 4; ++r) {
        float e = __expf(sc[ct][r] - mr[r]);
        sc[ct][r] = e;
        dsum[r] += e;
      }
#pragma unroll
    for (int off = 8; off; off >>= 1)
#pragma unroll
      for (int r = 0; r < 4; ++r) dsum[r] += __shfl_xor(dsum[r], off, 64);
    float rd[4];
#pragma unroll
    for (int r = 0; r < 4; ++r) rd[r] = 1.f / dsum[r];

    // ---- O = P V over two V chunks of 128 keys ----
    f32x4 o[4];
#pragma unroll
    for (int nt = 0; nt < 4; ++nt) o[nt] = (f32x4){0.f, 0.f, 0.f, 0.f};

#pragma unroll
    for (int c = 0; c < 2; ++c) {
      {
        int d0 = w * 8;
#pragma unroll
        for (int it = 0; it < 2; ++it) {
          int sl = it * 64 + lane;
          bf16x8 vv = *reinterpret_cast<const bf16x8*>(Vg + (size_t)(c * 128 + sl) * DH + d0);
#pragma unroll
          for (int j = 0; j < 8; ++j) {
            int u = (sl >> 3) ^ j;
            stage[(d0 + j) * 128 + u * 8 + (sl & 7)] = vv[j];
          }
        }
      }
      __syncthreads();
#pragma unroll
      for (int ctl = 0; ctl < 8; ++ctl) {
        int sl = ctl * 16 + l15;
        int u  = sl >> 3;
#pragma unroll
        for (int r = 0; r < 4; ++r) {
          int row = lk * 4 + r;
          Pw[row * 128 + ((u ^ (row & 7)) * 8) + (sl & 7)] = f2n(sc[c * 8 + ctl][r]);
        }
      }
#pragma unroll
      for (int ks = 0; ks < 4; ++ks) {
        bf16x8 pf = *reinterpret_cast<const bf16x8*>(
            &Pw[l15 * 128 + (((ks * 4 + lk) ^ (l15 & 7)) * 8)]);
#pragma unroll
        for (int nt = 0; nt < 4; ++nt) {
          int dd = nt * 16 + l15;
          bf16x8 vf = *reinterpret_cast<const bf16x8*>(
              &stage[dd * 128 + (((ks * 4 + lk) ^ (dd & 7)) * 8)]);
          o[nt] = __builtin_amdgcn_mfma_f32_16x16x32_bf16(pf, vf, o[nt], 0, 0, 0);
        }
      }
      __syncthreads();
    }

#pragma unroll
    for (int nt = 0; nt < 4; ++nt)
#pragma unroll
      for (int r = 0; r < 4; ++r) {
        int t = qt * 16 + lk * 4 + r;
        int d = nt * 16 + l15;
        att[(((size_t)b * TT + t) * HH + h) * DH + d] = f2b(o[nt][r] * rd[r]);
      }
    __syncthreads();
  }
}

// ---------------------------------------------------------------------------
// Loss + d_out write from fp32 logits scratch. 1024 blocks x 4 waves; each
// wave handles 8 rows; ONE atomic per block.
// ---------------------------------------------------------------------------
__global__ __launch_bounds__(256) void loss_kernel(
    const float* __restrict__ logits, const int* __restrict__ targets,
    void* __restrict__ out, float* __restrict__ loss,
    const int* __restrict__ flag)
{
  __shared__ float wsums[4];
  int wid = threadIdx.x >> 6, lane = threadIdx.x & 63;
  int fl = flag[0];
  float wacc = 0.f;

  for (int i = 0; i < 8; ++i) {
    int r = (blockIdx.x * 4 + wid) * 8 + i;
    const float* lr = logits + (size_t)r * VV;
    float a0 = lr[lane];
    float a1 = (lane == 0) ? lr[64] : -1e30f;

    if (fl) {
      float* o = (float*)out;
      o[(size_t)r * VV + lane] = a0;
      if (lane == 0) o[(size_t)r * VV + 64] = a1;
    } else {
      bf16* o = (bf16*)out;
      o[(size_t)r * VV + lane] = f2b(a0);
      if (lane == 0) o[(size_t)r * VV + 64] = f2b(a1);
    }

    float m = fmaxf(a0, a1);
#pragma unroll
    for (int off = 32; off; off >>= 1) m = fmaxf(m, __shfl_xor(m, off, 64));
    float e = __expf(a0 - m) + ((lane == 0) ? __expf(a1 - m) : 0.f);
#pragma unroll
    for (int off = 32; off; off >>= 1) e += __shfl_xor(e, off, 64);
    float logZ = m + logf(e);
    int tgt = targets[r];
    float contrib = (lane == tgt) ? (a0 - logZ) : 0.f;
    if (lane == 0 && tgt == 64) contrib = a1 - logZ;
#pragma unroll
    for (int off = 32; off; off >>= 1) contrib += __shfl_xor(contrib, off, 64);
    wacc += contrib;
  }

  if (lane == 0) wsums[wid] = wacc;
  __syncthreads();
  if (threadIdx.x == 0)
    atomicAdd(loss, -(wsums[0] + wsums[1] + wsums[2] + wsums[3]));
}

__global__ void finalize_kernel(const float* __restrict__ loss, void* __restrict__ out,
                                const int* __restrict__ flag)
{
  float v = loss[0] * (1.f / BT);
  if (flag[0]) ((float*)out)[(size_t)BT * VV] = v;
  else         ((bf16*)out)[(size_t)BT * VV]  = f2b(v);
}

// ---------------------------------------------------------------------------
extern "C" void kernel_launch(void* const* d_in, const int* in_sizes, int n_in,
                              void* d_out, int out_size, void* d_ws, size_t ws_size,
                              hipStream_t stream)
{
  const int* idx     = (const int*)d_in[0];
  const int* targets = (const int*)d_in[1];
  const void* tok  = d_in[2];
  const void* pos  = d_in[3];
  const void* Wq   = d_in[4];
  const void* Wk   = d_in[5];
  const void* Wv   = d_in[6];
  const void* Wo   = d_in[7];
  const void* bo   = d_in[8];
  const void* W1   = d_in[9];
  const void* b1   = d_in[10];
  const void* W2   = d_in[11];
  const void* b2   = d_in[12];
  const void* ln1g = d_in[13];
  const void* ln1b = d_in[14];
  const void* ln2g = d_in[15];
  const void* ln2b = d_in[16];
  const void* lnfg = d_in[17];
  const void* lnfb = d_in[18];
  const void* Wlm  = d_in[19];
  const void* blm  = d_in[20];

  char* ws = (char*)d_ws;
  size_t off = 0;
  auto alloc = [&](size_t bytes) { void* p = ws + off; off += (bytes + 255) & ~(size_t)255; return p; };

  bf16*  x   = (bf16*)alloc((size_t)BT * CC * 2);             // 25.2 MB (bf16 residual)
  bf16*  xn  = (bf16*)alloc((size_t)BT * CC * 2);             // 25.2 MB
  bf16*  qb  = (bf16*)alloc((size_t)BB * HH * TT * DH * 2);   // 16.8 MB x3 (contiguous)
  bf16*  kb  = (bf16*)alloc((size_t)BB * HH * TT * DH * 2);
  bf16*  vb  = (bf16*)alloc((size_t)BB * HH * TT * DH * 2);
  bf16*  att = (bf16*)alloc((size_t)BT * 256 * 2);            // 16.8 MB
  float* logits = (float*)att;  // logits scratch aliases dead att (8.5MB <= 16.8MB)
  // canonical bf16 weights
  bf16* c_tok  = (bf16*)alloc((size_t)VV * CC * 2);
  bf16* c_pos  = (bf16*)alloc((size_t)TT * CC * 2);
  bf16* wqkvT  = (bf16*)alloc((size_t)LL * 768 * CC * 2);     // B^T for fused QKV
  bf16* woT    = (bf16*)alloc((size_t)LL * CC * 256 * 2);     // B^T [C][256]
  bf16* w1T    = (bf16*)alloc((size_t)LL * FFD * CC * 2);     // B^T [FFD][C]
  bf16* w2T    = (bf16*)alloc((size_t)LL * CC * FFD * 2);     // B^T [C][FFD]
  bf16* wlmT   = (bf16*)alloc((size_t)128 * CC * 2);          // B^T [128][C], rows>=65 zero
  bf16* c_bo   = (bf16*)alloc((size_t)LL * CC * 2);
  bf16* c_b1   = (bf16*)alloc((size_t)LL * FFD * 2);
  bf16* c_b2   = (bf16*)alloc((size_t)LL * CC * 2);
  bf16* c_l1g  = (bf16*)alloc((size_t)LL * CC * 2);
  bf16* c_l1b  = (bf16*)alloc((size_t)LL * CC * 2);
  bf16* c_l2g  = (bf16*)alloc((size_t)LL * CC * 2);
  bf16* c_l2b  = (bf16*)alloc((size_t)LL * CC * 2);
  bf16* c_lfg  = (bf16*)alloc((size_t)CC * 2);
  bf16* c_lfb  = (bf16*)alloc((size_t)CC * 2);
  bf16* c_blm  = (bf16*)alloc((size_t)VV * 2);
  float* loss  = (float*)alloc(256);
  int*   flag  = (int*)alloc(256);

  // FF intermediate: full-size if ws permits, else 2-chunk aliased over q/k/v.
  size_t ff1_full_bytes = (size_t)BT * FFD * 2;               // 100.7 MB
  int    nchunks;
  int    fch;
  bf16*  ff1;
  if (ws_size - off >= ff1_full_bytes + 256) {
    ff1 = (bf16*)alloc(ff1_full_bytes);
    nchunks = 1; fch = BT;
  } else {
    ff1 = qb;
    nchunks = 2; fch = BT / 2;
  }

  hipMemsetAsync(loss, 0, 4, stream);

  detect_kernel<<<1, 256, 0, stream>>>((const unsigned short*)tok, flag);

  {
    ConvBatch cb;
    const void* srcs[NSEG] = {tok, pos, bo, b1, b2, ln1g, ln1b, ln2g, ln2b, lnfg, lnfb, blm};
    bf16* dsts[NSEG] = {c_tok, c_pos, c_bo, c_b1, c_b2, c_l1g, c_l1b, c_l2g, c_l2b, c_lfg, c_lfb, c_blm};
    int lens[NSEG] = {VV * CC, TT * CC, LL * CC, LL * FFD, LL * CC, LL * CC, LL * CC,
                      LL * CC, LL * CC, CC, CC, VV};
    int maxlen = 0;
    for (int i = 0; i < NSEG; ++i) {
      cb.src[i] = srcs[i]; cb.dst[i] = dsts[i]; cb.len[i] = lens[i];
      if (lens[i] > maxlen) maxlen = lens[i];
    }
    convert_batch_kernel<<<dim3((maxlen + 255) / 256, NSEG), 256, 0, stream>>>(cb, flag);
  }

  {
    int tq = LL * 768 * CC;
    repack_qkvT<<<(tq + 255) / 256, 256, 0, stream>>>(Wq, Wk, Wv, wqkvT, flag);
    int tw = T1 + 2 * T2 + T3;
    prep_weights<<<(tw + 255) / 256, 256, 0, stream>>>(Wo, W1, W2, Wlm,
                                                       woT, w1T, w2T, wlmT, flag);
  }

  embed_kernel<<<(BT * 48 + 255) / 256, 256, 0, stream>>>(idx, c_tok, c_pos, x);

  for (int l = 0; l < LL; ++l) {
    ln_kernel<<<BT / 4, 256, 0, stream>>>(x, xn, c_l1g + l * CC, c_l1b + l * CC);

    // QKV: N=768 -> BN=128 tiles, grid (6,256)=1536 blocks
    mfma_gemm<OUT_QKV, false, 128><<<dim3(768 / 128, BT / 128), 256, 0, stream>>>(
        xn, wqkvT + (size_t)l * 768 * CC, nullptr, qb, BT, 768, CC);

    attn_mfma_kernel<<<BB * HH, 512, 0, stream>>>(qb, kb, vb, att);

    // Wo: N=384 -> BN=64 tiles, grid (6,256)=1536 blocks
    mfma_gemm<OUT_RES, false, 64><<<dim3(CC / 64, BT / 128), 256, 0, stream>>>(
        att, woT + (size_t)l * CC * 256, c_bo + l * CC, x, BT, CC, 256);

    ln_kernel<<<BT / 4, 256, 0, stream>>>(x, xn, c_l2g + l * CC, c_l2b + l * CC);

    for (int ch = 0; ch < nchunks; ++ch) {
      const bf16* Ach = xn + (size_t)ch * fch * CC;
      // FF1: N=1536 -> BN=128 tiles, grid (12,256)=3072 blocks
      mfma_gemm<OUT_BF16, true, 128><<<dim3(FFD / 128, fch / 128), 256, 0, stream>>>(
          Ach, w1T + (size_t)l * FFD * CC, c_b1 + l * FFD, ff1, fch, FFD, CC);
      // FF2: N=384 -> BN=64 tiles, grid (6, fch/128) = 1536 blocks
      mfma_gemm<OUT_RES, false, 64><<<dim3(CC / 64, fch / 128), 256, 0, stream>>>(
          ff1, w2T + (size_t)l * CC * FFD, c_b2 + l * CC, x + (size_t)ch * fch * CC, fch, CC, FFD);
    }
  }

  ln_kernel<<<BT / 4, 256, 0, stream>>>(x, xn, c_lfg, c_lfb);
  // LM head: [BT,384] x [384,65->128] via MFMA, BN=64 -> grid (2,256)=512
  mfma_gemm<OUT_LMH, false, 64><<<dim3(2, BT / 128), 256, 0, stream>>>(
      xn, wlmT, c_blm, logits, BT, 128, CC);
  loss_kernel<<<1024, 256, 0, stream>>>(logits, targets, d_out, loss, flag);
  finalize_kernel<<<1, 1, 0, stream>>>(loss, d_out, flag);
}